// Round 1
// baseline (446.505 us; speedup 1.0000x reference)
//
#include <hip/hip_runtime.h>
#include <hip/hip_bf16.h>
#include <math.h>

// ---------------------------------------------------------------------------
// RealSymplecticReactionDiffusion2D — baseline multi-kernel implementation
//  B=8, N=4096 (64x64), d=768, k_steps=4 (read from device)
// Stages:
//  1) pool_partial + pool_reduce  -> pooled[8][768]   (deterministic 2-stage)
//  2) gamma_kernel                -> gamma[8][768]    (softplus clamp 0.05)
//  3) cvt_bf16 (W_out -> bf16)
//  4) pde_kernel (per (b,c) 64x64 grid in LDS, fp32)  -> uv [8][1536][4096] bf16
//  5) transpose_uv  -> A [32768][1536] bf16 (row-major K-contiguous)
//  6) gemm_kernel (bf16 MFMA 16x16x32, 128x128 tile) + epilogue (+ x*D)
// ---------------------------------------------------------------------------

typedef __attribute__((ext_vector_type(8))) short short8v;
typedef __attribute__((ext_vector_type(4))) float float4v;

static __device__ __forceinline__ unsigned short f2bf(float f) {
  unsigned u = __builtin_bit_cast(unsigned, f);
  u += 0x7FFFu + ((u >> 16) & 1u);   // round-to-nearest-even
  return (unsigned short)(u >> 16);
}

static __device__ __forceinline__ float softplusf(float x) {
  return (x > 20.0f) ? x : log1pf(expf(x));
}

// ---------------- pooling (deterministic, no atomics) ----------------
__global__ void pool_partial_kernel(const float* __restrict__ x, float* __restrict__ partial) {
  // grid (3, 32, 8), block 256: partial[nchunk][b][c]
  const int c = blockIdx.x * 256 + threadIdx.x;     // 0..767
  const int n0 = blockIdx.y * 128;
  const int b = blockIdx.z;
  const float* xp = x + ((size_t)b * 4096 + n0) * 768 + c;
  float s = 0.0f;
  #pragma unroll 4
  for (int i = 0; i < 128; ++i) s += xp[(size_t)i * 768];
  partial[((size_t)blockIdx.y * 8 + b) * 768 + c] = s;
}

__global__ void pool_reduce_kernel(const float* __restrict__ partial, float* __restrict__ pooled) {
  const int idx = blockIdx.x * 256 + threadIdx.x;   // 0..6143 = b*768+c
  float s = 0.0f;
  #pragma unroll
  for (int j = 0; j < 32; ++j) s += partial[(size_t)j * 6144 + idx];
  pooled[idx] = s * (1.0f / 4096.0f);
}

// ---------------- diffusion gate ----------------
__global__ void gamma_kernel(const float* __restrict__ pooled, const float* __restrict__ Wg,
                             const float* __restrict__ bg, float* __restrict__ gamma) {
  // grid 1536 x 256 threads; each wave computes one output o = b*768 + j
  const int lane = threadIdx.x & 63;
  const int w = threadIdx.x >> 6;
  const int o = blockIdx.x * 4 + w;
  const int b = o / 768;
  const int j = o - b * 768;
  const float* pr = pooled + b * 768;
  const float* wr = Wg + (size_t)j * 768;
  float s = 0.0f;
  #pragma unroll
  for (int c = lane; c < 768; c += 64) s += pr[c] * wr[c];
  #pragma unroll
  for (int off = 32; off > 0; off >>= 1) s += __shfl_down(s, off);
  if (lane == 0) {
    float gin = s + bg[j];
    gamma[o] = fminf(softplusf(gin), 0.05f);
  }
}

// ---------------- W_out -> bf16 ----------------
__global__ void cvt_bf16_kernel(const float* __restrict__ src, unsigned short* __restrict__ dst, int n) {
  int i = blockIdx.x * 256 + threadIdx.x;
  if (i < n) dst[i] = f2bf(src[i]);
}

// ---------------- symplectic reaction-diffusion PDE ----------------
__global__ __launch_bounds__(256) void pde_kernel(
    const float* __restrict__ x, const float* __restrict__ gamma,
    const float* __restrict__ alpha, const float* __restrict__ beta,
    const int* __restrict__ kp, unsigned short* __restrict__ uv) {
  __shared__ float u[4096];
  __shared__ float v[4096];
  const int c = blockIdx.x;   // channel 0..767
  const int b = blockIdx.y;   // batch 0..7
  const int t = threadIdx.x;  // 0..255

  int ks = *kp; if (ks < 1) ks = 1;
  const float dt = 1.0f / (float)ks;
  const float hdt = 0.5f * dt;
  const float ae = 0.2f * tanhf(alpha[c]);
  const float be = fmaxf(softplusf(beta[c]), 1e-4f);
  const float g = gamma[b * 768 + c];
  const float c1 = 0.5f * dt * g;
  const float c2 = dt * g;

  // load channel (strided over d; L2/L3 dedups across neighboring c-blocks)
  const float* xp = x + (size_t)b * 4096 * 768 + c;
  for (int i = t; i < 4096; i += 256) { u[i] = xp[(size_t)i * 768]; v[i] = 0.0f; }
  __syncthreads();

  for (int s = 0; s < ks; ++s) {
    // reaction, first half-step (own cells only)
    #pragma unroll
    for (int kk = 0; kk < 16; ++kk) {
      const int i = t + kk * 256;
      const float uu = u[i], vv = v[i];
      const float q = uu * uu + vv * vv;
      const float rate = fminf(fmaxf(ae - be * q, -1.0f), 1.0f);
      u[i] = uu + hdt * rate * uu;
      v[i] = vv + hdt * rate * vv;
    }
    __syncthreads();
    // v_half = v - c1 * lap(u)
    #pragma unroll
    for (int kk = 0; kk < 16; ++kk) {
      const int i = t + kk * 256;
      const int r = i & ~63;
      const float lap = u[r | ((i + 1) & 63)] + u[r | ((i + 63) & 63)]
                      + u[(i + 64) & 4095] + u[(i + 4032) & 4095] - 4.0f * u[i];
      v[i] -= c1 * lap;
    }
    __syncthreads();
    // u_new = u + c2 * lap(v_half)
    #pragma unroll
    for (int kk = 0; kk < 16; ++kk) {
      const int i = t + kk * 256;
      const int r = i & ~63;
      const float lap = v[r | ((i + 1) & 63)] + v[r | ((i + 63) & 63)]
                      + v[(i + 64) & 4095] + v[(i + 4032) & 4095] - 4.0f * v[i];
      u[i] += c2 * lap;
    }
    __syncthreads();
    // v_new = v_half - c1 * lap(u_new)
    #pragma unroll
    for (int kk = 0; kk < 16; ++kk) {
      const int i = t + kk * 256;
      const int r = i & ~63;
      const float lap = u[r | ((i + 1) & 63)] + u[r | ((i + 63) & 63)]
                      + u[(i + 64) & 4095] + u[(i + 4032) & 4095] - 4.0f * u[i];
      v[i] -= c1 * lap;
    }
    __syncthreads();
    // reaction, second half-step (own cells only; next iter's reaction is also
    // own-cell so no barrier needed between loop iterations here)
    #pragma unroll
    for (int kk = 0; kk < 16; ++kk) {
      const int i = t + kk * 256;
      const float uu = u[i], vv = v[i];
      const float q = uu * uu + vv * vv;
      const float rate = fminf(fmaxf(ae - be * q, -1.0f), 1.0f);
      u[i] = uu + hdt * rate * uu;
      v[i] = vv + hdt * rate * vv;
    }
    __syncthreads();
  }

  // write out channel-major bf16: uv[b][c][n] = u, uv[b][768+c][n] = v
  unsigned short* up = uv + ((size_t)b * 1536 + c) * 4096;
  unsigned short* vp = up + (size_t)768 * 4096;
  for (int i = t; i < 4096; i += 256) { up[i] = f2bf(u[i]); vp[i] = f2bf(v[i]); }
}

// ---------------- transpose uv [8][1536][4096] -> A [32768][1536] ----------------
__global__ void transpose_uv_kernel(const unsigned short* __restrict__ src,
                                    unsigned short* __restrict__ dst) {
  // grid (64, 24, 8), block 256
  __shared__ unsigned short tile[64][66];
  const int n0 = blockIdx.x * 64;
  const int k0 = blockIdx.y * 64;
  const int b = blockIdx.z;
  const int tx = threadIdx.x & 63;
  const int ty = threadIdx.x >> 6;   // 0..3
  const size_t sbase = ((size_t)b * 1536 + k0) * 4096 + n0;
  #pragma unroll
  for (int j = 0; j < 16; ++j) {
    const int k = ty + 4 * j;
    tile[k][tx] = src[sbase + (size_t)k * 4096 + tx];
  }
  __syncthreads();
  const size_t dbase = ((size_t)b * 4096 + n0) * 1536 + k0;
  #pragma unroll
  for (int j = 0; j < 16; ++j) {
    const int n = ty + 4 * j;
    dst[dbase + (size_t)n * 1536 + tx] = tile[tx][n];
  }
}

// ---------------- bf16 MFMA GEMM: out = A @ W^T + x*D ----------------
__global__ __launch_bounds__(256) void gemm_kernel(
    const unsigned short* __restrict__ A,   // [32768][1536] bf16
    const unsigned short* __restrict__ Bt,  // [768][1536]  bf16 (W_out, B^T layout)
    const float* __restrict__ x,            // [32768][768]
    const float* __restrict__ Dv,           // [768]
    float* __restrict__ out) {              // [32768][768]
  __shared__ __align__(16) unsigned short Als[128 * 64];
  __shared__ __align__(16) unsigned short Bls[128 * 64];
  const int tid = threadIdx.x;
  const int lane = tid & 63;
  const int w = tid >> 6;       // wave 0..3
  const int wr = w >> 1;        // wave row (2x2 waves, each 64x64 of C)
  const int wc = w & 1;
  const int m0 = blockIdx.x * 128;
  const int n0 = blockIdx.y * 128;

  float4v acc[4][4];
  #pragma unroll
  for (int a = 0; a < 4; ++a)
    #pragma unroll
    for (int bq = 0; bq < 4; ++bq)
      acc[a][bq] = (float4v){0.f, 0.f, 0.f, 0.f};

  for (int k0 = 0; k0 < 1536; k0 += 64) {
    // stage A-tile [128][64] and B-tile [128][64] via direct global->LDS (16B/lane)
    #pragma unroll
    for (int i = 0; i < 4; ++i) {
      const int rowblk = (w * 4 + i) * 8;        // wave-uniform
      const int row = rowblk + (lane >> 3);
      const int kk = k0 + (lane & 7) * 8;
      __builtin_amdgcn_global_load_lds(
          (const __attribute__((address_space(1))) void*)(A + (size_t)(m0 + row) * 1536 + kk),
          (__attribute__((address_space(3))) void*)(&Als[rowblk * 64]), 16, 0, 0);
      __builtin_amdgcn_global_load_lds(
          (const __attribute__((address_space(1))) void*)(Bt + (size_t)(n0 + row) * 1536 + kk),
          (__attribute__((address_space(3))) void*)(&Bls[rowblk * 64]), 16, 0, 0);
    }
    __syncthreads();
    #pragma unroll
    for (int ksub = 0; ksub < 2; ++ksub) {
      short8v af[4], bf[4];
      #pragma unroll
      for (int mi = 0; mi < 4; ++mi)
        af[mi] = *(const short8v*)(&Als[(wr * 64 + mi * 16 + (lane & 15)) * 64 + ksub * 32 + (lane >> 4) * 8]);
      #pragma unroll
      for (int ni = 0; ni < 4; ++ni)
        bf[ni] = *(const short8v*)(&Bls[(wc * 64 + ni * 16 + (lane & 15)) * 64 + ksub * 32 + (lane >> 4) * 8]);
      #pragma unroll
      for (int mi = 0; mi < 4; ++mi)
        #pragma unroll
        for (int ni = 0; ni < 4; ++ni)
          acc[mi][ni] = __builtin_amdgcn_mfma_f32_16x16x32_bf16(af[mi], bf[ni], acc[mi][ni], 0, 0, 0);
    }
    __syncthreads();
  }

  // epilogue: out = acc + x*D  (C/D layout: col=lane&15, row=(lane>>4)*4+r)
  #pragma unroll
  for (int ni = 0; ni < 4; ++ni) {
    const int col = n0 + wc * 64 + ni * 16 + (lane & 15);
    const float dcol = Dv[col];
    #pragma unroll
    for (int mi = 0; mi < 4; ++mi) {
      #pragma unroll
      for (int r = 0; r < 4; ++r) {
        const int row = m0 + wr * 64 + mi * 16 + (lane >> 4) * 4 + r;
        const size_t idx = (size_t)row * 768 + col;
        out[idx] = acc[mi][ni][r] + x[idx] * dcol;
      }
    }
  }
}

// ---------------------------------------------------------------------------
extern "C" void kernel_launch(void* const* d_in, const int* in_sizes, int n_in,
                              void* d_out, int out_size, void* d_ws, size_t ws_size,
                              hipStream_t stream) {
  const float* x     = (const float*)d_in[0];
  const float* Wg    = (const float*)d_in[1];
  const float* bg    = (const float*)d_in[2];
  const float* alpha = (const float*)d_in[3];
  const float* beta  = (const float*)d_in[4];
  const float* Wout  = (const float*)d_in[5];
  const float* Dv    = (const float*)d_in[6];
  const int*   kp    = (const int*)d_in[7];
  float* out = (float*)d_out;

  // workspace layout (total ~195 MiB)
  char* ws = (char*)d_ws;
  unsigned short* A   = (unsigned short*)(ws);                 // 32768*1536*2   = 100663296
  unsigned short* uv  = (unsigned short*)(ws + 100663296);     // 8*1536*4096*2  = 100663296
  unsigned short* Wb  = (unsigned short*)(ws + 201326592);     // 768*1536*2     = 2359296
  float* partial      = (float*)(ws + 203685888);              // 32*8*768*4     = 786432
  float* pooled       = (float*)(ws + 204472320);              // 6144*4
  float* gam          = (float*)(ws + 204496896);              // 6144*4

  pool_partial_kernel<<<dim3(3, 32, 8), 256, 0, stream>>>(x, partial);
  pool_reduce_kernel<<<24, 256, 0, stream>>>(partial, pooled);
  gamma_kernel<<<1536, 256, 0, stream>>>(pooled, Wg, bg, gam);
  cvt_bf16_kernel<<<(768 * 1536 + 255) / 256, 256, 0, stream>>>(Wout, Wb, 768 * 1536);
  pde_kernel<<<dim3(768, 8), 256, 0, stream>>>(x, gam, alpha, beta, kp, uv);
  transpose_uv_kernel<<<dim3(64, 24, 8), 256, 0, stream>>>(uv, A);
  gemm_kernel<<<dim3(256, 6), 256, 0, stream>>>(A, Wb, x, Dv, out);
}

// Round 4
// 404.987 us; speedup vs baseline: 1.1025x; 1.1025x over previous
//
#include <hip/hip_runtime.h>
#include <hip/hip_bf16.h>
#include <math.h>

// ---------------------------------------------------------------------------
// RealSymplecticReactionDiffusion2D — round 2 kernel (resubmit #2, infra failures)
//  B=8, N=4096 (64x64), d=768, k_steps=4 (read from device)
// Stages:
//  1) pool_partial + pool_reduce  -> pooled[8][768]   (deterministic 2-stage)
//  2) gamma_kernel                -> gamma[8][768]    (softplus clamp 0.05)
//  3) cvt_bf16 (W_out -> bf16)
//  4) transpose_x: x [B,N,768] -> xT [B,768,N]  (fp32, LDS-tiled, coalesced)
//  5) pde_kernel: register-resident u/v (wave=16-row strip, lane=column),
//     left/right via __shfl, up/down via register + LDS halo. -> uv bf16
//  6) transpose_uv  -> A [32768][1536] bf16 (row-major K-contiguous)
//  7) gemm_kernel (bf16 MFMA 16x16x32, 128x128 tile) + epilogue (+ x*D)
//  NOTE: xT shares the A workspace buffer (xT dead before A is written).
// ---------------------------------------------------------------------------

typedef __attribute__((ext_vector_type(8))) short short8v;
typedef __attribute__((ext_vector_type(4))) float float4v;

static __device__ __forceinline__ unsigned short f2bf(float f) {
  unsigned u = __builtin_bit_cast(unsigned, f);
  u += 0x7FFFu + ((u >> 16) & 1u);   // round-to-nearest-even
  return (unsigned short)(u >> 16);
}

static __device__ __forceinline__ float softplusf(float x) {
  return (x > 20.0f) ? x : log1pf(expf(x));
}

// ---------------- pooling (deterministic, no atomics) ----------------
__global__ void pool_partial_kernel(const float* __restrict__ x, float* __restrict__ partial) {
  // grid (3, 32, 8), block 256: partial[nchunk][b][c]
  const int c = blockIdx.x * 256 + threadIdx.x;     // 0..767
  const int n0 = blockIdx.y * 128;
  const int b = blockIdx.z;
  const float* xp = x + ((size_t)b * 4096 + n0) * 768 + c;
  float s = 0.0f;
  #pragma unroll 4
  for (int i = 0; i < 128; ++i) s += xp[(size_t)i * 768];
  partial[((size_t)blockIdx.y * 8 + b) * 768 + c] = s;
}

__global__ void pool_reduce_kernel(const float* __restrict__ partial, float* __restrict__ pooled) {
  const int idx = blockIdx.x * 256 + threadIdx.x;   // 0..6143 = b*768+c
  float s = 0.0f;
  #pragma unroll
  for (int j = 0; j < 32; ++j) s += partial[(size_t)j * 6144 + idx];
  pooled[idx] = s * (1.0f / 4096.0f);
}

// ---------------- diffusion gate ----------------
__global__ void gamma_kernel(const float* __restrict__ pooled, const float* __restrict__ Wg,
                             const float* __restrict__ bg, float* __restrict__ gamma) {
  // grid 1536 x 256 threads; each wave computes one output o = b*768 + j
  const int lane = threadIdx.x & 63;
  const int w = threadIdx.x >> 6;
  const int o = blockIdx.x * 4 + w;
  const int b = o / 768;
  const int j = o - b * 768;
  const float* pr = pooled + b * 768;
  const float* wr = Wg + (size_t)j * 768;
  float s = 0.0f;
  #pragma unroll
  for (int c = lane; c < 768; c += 64) s += pr[c] * wr[c];
  #pragma unroll
  for (int off = 32; off > 0; off >>= 1) s += __shfl_down(s, off);
  if (lane == 0) {
    float gin = s + bg[j];
    gamma[o] = fminf(softplusf(gin), 0.05f);
  }
}

// ---------------- W_out -> bf16 ----------------
__global__ void cvt_bf16_kernel(const float* __restrict__ src, unsigned short* __restrict__ dst, int n) {
  int i = blockIdx.x * 256 + threadIdx.x;
  if (i < n) dst[i] = f2bf(src[i]);
}

// ---------------- transpose x [B,N,768] -> xT [B,768,N] ----------------
__global__ __launch_bounds__(256) void transpose_x_kernel(const float* __restrict__ x,
                                                          float* __restrict__ xT) {
  __shared__ float tile[64][65];
  const int c0 = blockIdx.x * 64;   // 12 tiles
  const int n0 = blockIdx.y * 64;   // 64 tiles
  const int b  = blockIdx.z;        // 8
  const int tl = threadIdx.x & 63;
  const int tw = threadIdx.x >> 6;  // 0..3
  const float* src = x + ((size_t)b * 4096 + n0) * 768 + c0;
  #pragma unroll
  for (int j = 0; j < 16; ++j) {
    const int n = j * 4 + tw;
    tile[n][tl] = src[(size_t)n * 768 + tl];
  }
  __syncthreads();
  float* dst = xT + ((size_t)b * 768 + c0) * 4096 + n0;
  #pragma unroll
  for (int j = 0; j < 16; ++j) {
    const int cc = j * 4 + tw;
    dst[(size_t)cc * 4096 + tl] = tile[tl][cc];
  }
}

// ---------------- symplectic reaction-diffusion PDE (register-resident) -----
// Wave w owns rows w*16..w*16+15; lane l owns column l. u[16],v[16] in VGPRs.
// Left/right neighbor: __shfl lane+-1 (periodic). Up/down: registers, except
// strip boundary rows exchanged through a small double-buffered LDS halo.
__global__ __launch_bounds__(256) void pde_kernel(
    const float* __restrict__ xT, const float* __restrict__ gamma,
    const float* __restrict__ alpha, const float* __restrict__ beta,
    const int* __restrict__ kp, unsigned short* __restrict__ uv) {
  __shared__ float haloT[2][4][64];   // [buf][wave][col] = wave's row w*16
  __shared__ float haloB[2][4][64];   // [buf][wave][col] = wave's row w*16+15
  const int c = blockIdx.x;   // channel 0..767
  const int b = blockIdx.y;   // batch 0..7
  const int l = threadIdx.x & 63;
  const int w = threadIdx.x >> 6;   // 0..3

  int ks = *kp; if (ks < 1) ks = 1;
  const float dt = 1.0f / (float)ks;
  const float hdt = 0.5f * dt;
  const float ae = 0.2f * tanhf(alpha[c]);
  const float be = fmaxf(softplusf(beta[c]), 1e-4f);
  const float g = gamma[b * 768 + c];
  const float c1n = -0.5f * dt * g;   // v -= c1*lap  ->  v += c1n*lap
  const float c2p = dt * g;

  const int idxL = (l + 63) & 63;
  const int idxR = (l + 1) & 63;
  const int wu = (w + 1) & 3;   // wave holding rows below (next strip)
  const int wd = (w + 3) & 3;   // wave holding rows above (prev strip)

  float u[16], v[16];
  const float* xp = xT + ((size_t)b * 768 + c) * 4096 + (size_t)(w * 16) * 64 + l;
  #pragma unroll
  for (int r = 0; r < 16; ++r) { u[r] = xp[(size_t)r * 64]; v[r] = 0.0f; }

  int buf = 0;

  // G[r] += COEF * lap(F[r]); one barrier per phase, halo double-buffered.
  #define LAP_PHASE(F, G, COEF)                                              \
    {                                                                        \
      haloT[buf][w][l] = F[0];                                               \
      haloB[buf][w][l] = F[15];                                              \
      __syncthreads();                                                       \
      const float up0  = haloB[buf][wd][l];                                  \
      const float dn15 = haloT[buf][wu][l];                                  \
      _Pragma("unroll")                                                      \
      for (int r = 0; r < 16; ++r) {                                         \
        const float lf = __shfl(F[r], idxL);                                 \
        const float rt = __shfl(F[r], idxR);                                 \
        const float up = (r == 0)  ? up0  : F[r - 1];                        \
        const float dn = (r == 15) ? dn15 : F[r + 1];                        \
        const float lap = (lf + rt) + (up + dn) - 4.0f * F[r];               \
        G[r] = fmaf((COEF), lap, G[r]);                                      \
      }                                                                      \
      buf ^= 1;                                                              \
    }

  for (int s = 0; s < ks; ++s) {
    // reaction, first half-step (pure registers)
    #pragma unroll
    for (int r = 0; r < 16; ++r) {
      const float q = u[r] * u[r] + v[r] * v[r];
      const float rate = fminf(fmaxf(ae - be * q, -1.0f), 1.0f);
      const float t = hdt * rate;
      u[r] = fmaf(t, u[r], u[r]);
      v[r] = fmaf(t, v[r], v[r]);
    }
    // v_half = v - c1*lap(u);  u += c2*lap(v_half);  v = v_half - c1*lap(u)
    LAP_PHASE(u, v, c1n)
    LAP_PHASE(v, u, c2p)
    LAP_PHASE(u, v, c1n)
    // reaction, second half-step
    #pragma unroll
    for (int r = 0; r < 16; ++r) {
      const float q = u[r] * u[r] + v[r] * v[r];
      const float rate = fminf(fmaxf(ae - be * q, -1.0f), 1.0f);
      const float t = hdt * rate;
      u[r] = fmaf(t, u[r], u[r]);
      v[r] = fmaf(t, v[r], v[r]);
    }
  }
  #undef LAP_PHASE

  // write out channel-major bf16: uv[b][c][n] = u, uv[b][768+c][n] = v
  unsigned short* up = uv + ((size_t)b * 1536 + c) * 4096 + (size_t)(w * 16) * 64 + l;
  unsigned short* vp = up + (size_t)768 * 4096;
  #pragma unroll
  for (int r = 0; r < 16; ++r) {
    up[(size_t)r * 64] = f2bf(u[r]);
    vp[(size_t)r * 64] = f2bf(v[r]);
  }
}

// ---------------- transpose uv [8][1536][4096] -> A [32768][1536] ----------------
__global__ void transpose_uv_kernel(const unsigned short* __restrict__ src,
                                    unsigned short* __restrict__ dst) {
  // grid (64, 24, 8), block 256
  __shared__ unsigned short tile[64][66];
  const int n0 = blockIdx.x * 64;
  const int k0 = blockIdx.y * 64;
  const int b = blockIdx.z;
  const int tx = threadIdx.x & 63;
  const int ty = threadIdx.x >> 6;   // 0..3
  const size_t sbase = ((size_t)b * 1536 + k0) * 4096 + n0;
  #pragma unroll
  for (int j = 0; j < 16; ++j) {
    const int k = ty + 4 * j;
    tile[k][tx] = src[sbase + (size_t)k * 4096 + tx];
  }
  __syncthreads();
  const size_t dbase = ((size_t)b * 4096 + n0) * 1536 + k0;
  #pragma unroll
  for (int j = 0; j < 16; ++j) {
    const int n = ty + 4 * j;
    dst[dbase + (size_t)n * 1536 + tx] = tile[tx][n];
  }
}

// ---------------- bf16 MFMA GEMM: out = A @ W^T + x*D ----------------
__global__ __launch_bounds__(256) void gemm_kernel(
    const unsigned short* __restrict__ A,   // [32768][1536] bf16
    const unsigned short* __restrict__ Bt,  // [768][1536]  bf16 (W_out, B^T layout)
    const float* __restrict__ x,            // [32768][768]
    const float* __restrict__ Dv,           // [768]
    float* __restrict__ out) {              // [32768][768]
  __shared__ __align__(16) unsigned short Als[128 * 64];
  __shared__ __align__(16) unsigned short Bls[128 * 64];
  const int tid = threadIdx.x;
  const int lane = tid & 63;
  const int w = tid >> 6;       // wave 0..3
  const int wr = w >> 1;        // wave row (2x2 waves, each 64x64 of C)
  const int wc = w & 1;
  const int m0 = blockIdx.x * 128;
  const int n0 = blockIdx.y * 128;

  float4v acc[4][4];
  #pragma unroll
  for (int a = 0; a < 4; ++a)
    #pragma unroll
    for (int bq = 0; bq < 4; ++bq)
      acc[a][bq] = (float4v){0.f, 0.f, 0.f, 0.f};

  for (int k0 = 0; k0 < 1536; k0 += 64) {
    // stage A-tile [128][64] and B-tile [128][64] via direct global->LDS (16B/lane)
    #pragma unroll
    for (int i = 0; i < 4; ++i) {
      const int rowblk = (w * 4 + i) * 8;        // wave-uniform
      const int row = rowblk + (lane >> 3);
      const int kk = k0 + (lane & 7) * 8;
      __builtin_amdgcn_global_load_lds(
          (const __attribute__((address_space(1))) void*)(A + (size_t)(m0 + row) * 1536 + kk),
          (__attribute__((address_space(3))) void*)(&Als[rowblk * 64]), 16, 0, 0);
      __builtin_amdgcn_global_load_lds(
          (const __attribute__((address_space(1))) void*)(Bt + (size_t)(n0 + row) * 1536 + kk),
          (__attribute__((address_space(3))) void*)(&Bls[rowblk * 64]), 16, 0, 0);
    }
    __syncthreads();
    #pragma unroll
    for (int ksub = 0; ksub < 2; ++ksub) {
      short8v af[4], bf[4];
      #pragma unroll
      for (int mi = 0; mi < 4; ++mi)
        af[mi] = *(const short8v*)(&Als[(wr * 64 + mi * 16 + (lane & 15)) * 64 + ksub * 32 + (lane >> 4) * 8]);
      #pragma unroll
      for (int ni = 0; ni < 4; ++ni)
        bf[ni] = *(const short8v*)(&Bls[(wc * 64 + ni * 16 + (lane & 15)) * 64 + ksub * 32 + (lane >> 4) * 8]);
      #pragma unroll
      for (int mi = 0; mi < 4; ++mi)
        #pragma unroll
        for (int ni = 0; ni < 4; ++ni)
          acc[mi][ni] = __builtin_amdgcn_mfma_f32_16x16x32_bf16(af[mi], bf[ni], acc[mi][ni], 0, 0, 0);
    }
    __syncthreads();
  }

  // epilogue: out = acc + x*D  (C/D layout: col=lane&15, row=(lane>>4)*4+r)
  #pragma unroll
  for (int ni = 0; ni < 4; ++ni) {
    const int col = n0 + wc * 64 + ni * 16 + (lane & 15);
    const float dcol = Dv[col];
    #pragma unroll
    for (int mi = 0; mi < 4; ++mi) {
      #pragma unroll
      for (int r = 0; r < 4; ++r) {
        const int row = m0 + wr * 64 + mi * 16 + (lane >> 4) * 4 + r;
        const size_t idx = (size_t)row * 768 + col;
        out[idx] = acc[mi][ni][r] + x[idx] * dcol;
      }
    }
  }
}

// ---------------------------------------------------------------------------
extern "C" void kernel_launch(void* const* d_in, const int* in_sizes, int n_in,
                              void* d_out, int out_size, void* d_ws, size_t ws_size,
                              hipStream_t stream) {
  const float* x     = (const float*)d_in[0];
  const float* Wg    = (const float*)d_in[1];
  const float* bg    = (const float*)d_in[2];
  const float* alpha = (const float*)d_in[3];
  const float* beta  = (const float*)d_in[4];
  const float* Wout  = (const float*)d_in[5];
  const float* Dv    = (const float*)d_in[6];
  const int*   kp    = (const int*)d_in[7];
  float* out = (float*)d_out;

  // workspace layout (~195 MiB) — xT aliases A (xT dead before A is written)
  char* ws = (char*)d_ws;
  unsigned short* A   = (unsigned short*)(ws);                 // 32768*1536*2   = 100663296
  float* xT           = (float*)(ws);                          // 8*768*4096*4   = 100663296 (alias)
  unsigned short* uv  = (unsigned short*)(ws + 100663296);     // 8*1536*4096*2  = 100663296
  unsigned short* Wb  = (unsigned short*)(ws + 201326592);     // 768*1536*2     = 2359296
  float* partial      = (float*)(ws + 203685888);              // 32*8*768*4     = 786432
  float* pooled       = (float*)(ws + 204472320);              // 6144*4
  float* gam          = (float*)(ws + 204496896);              // 6144*4

  pool_partial_kernel<<<dim3(3, 32, 8), 256, 0, stream>>>(x, partial);
  pool_reduce_kernel<<<24, 256, 0, stream>>>(partial, pooled);
  gamma_kernel<<<1536, 256, 0, stream>>>(pooled, Wg, bg, gam);
  cvt_bf16_kernel<<<(768 * 1536 + 255) / 256, 256, 0, stream>>>(Wout, Wb, 768 * 1536);
  transpose_x_kernel<<<dim3(12, 64, 8), 256, 0, stream>>>(x, xT);
  pde_kernel<<<dim3(768, 8), 256, 0, stream>>>(xT, gam, alpha, beta, kp, uv);
  transpose_uv_kernel<<<dim3(64, 24, 8), 256, 0, stream>>>(uv, A);
  gemm_kernel<<<dim3(256, 6), 256, 0, stream>>>(A, Wb, x, Dv, out);
}

// Round 5
// 397.587 us; speedup vs baseline: 1.1230x; 1.0186x over previous
//
#include <hip/hip_runtime.h>
#include <hip/hip_bf16.h>
#include <math.h>

// ---------------------------------------------------------------------------
// RealSymplecticReactionDiffusion2D — round 4
//  B=8, N=4096 (64x64), d=768, k_steps=4 (read from device)
// Stages:
//  1) pool_partial + pool_reduce  -> pooled[8][768]   (deterministic 2-stage)
//  2) gamma_kernel                -> gamma[8][768]    (softplus clamp 0.05)
//  3) cvt_bf16 (W_out -> bf16)
//  4) transpose_x: x [B,N,768] -> xT [B,768,N]  (fp32, LDS-tiled, coalesced)
//  5) pde_kernel: register-resident u/v (wave=16-row strip, lane=column)
//  6) transpose_uv  -> A [32768][1536] bf16 (row-major K-contiguous)
//  7) gemm_kernel: bf16 MFMA 16x16x32, 128x128 tile, XOR-swizzled LDS
//     (linear gload_lds dest + inverse-swizzled global source + swizzled read
//      — rule #21 both-sides pattern; kills the 16-way bank conflict)
// ---------------------------------------------------------------------------

typedef __attribute__((ext_vector_type(8))) short short8v;
typedef __attribute__((ext_vector_type(4))) float float4v;

static __device__ __forceinline__ unsigned short f2bf(float f) {
  unsigned u = __builtin_bit_cast(unsigned, f);
  u += 0x7FFFu + ((u >> 16) & 1u);   // round-to-nearest-even
  return (unsigned short)(u >> 16);
}

static __device__ __forceinline__ float softplusf(float x) {
  return (x > 20.0f) ? x : log1pf(expf(x));
}

// ---------------- pooling (deterministic, no atomics) ----------------
__global__ void pool_partial_kernel(const float* __restrict__ x, float* __restrict__ partial) {
  // grid (3, 32, 8), block 256: partial[nchunk][b][c]
  const int c = blockIdx.x * 256 + threadIdx.x;     // 0..767
  const int n0 = blockIdx.y * 128;
  const int b = blockIdx.z;
  const float* xp = x + ((size_t)b * 4096 + n0) * 768 + c;
  float s = 0.0f;
  #pragma unroll 4
  for (int i = 0; i < 128; ++i) s += xp[(size_t)i * 768];
  partial[((size_t)blockIdx.y * 8 + b) * 768 + c] = s;
}

__global__ void pool_reduce_kernel(const float* __restrict__ partial, float* __restrict__ pooled) {
  const int idx = blockIdx.x * 256 + threadIdx.x;   // 0..6143 = b*768+c
  float s = 0.0f;
  #pragma unroll
  for (int j = 0; j < 32; ++j) s += partial[(size_t)j * 6144 + idx];
  pooled[idx] = s * (1.0f / 4096.0f);
}

// ---------------- diffusion gate ----------------
__global__ void gamma_kernel(const float* __restrict__ pooled, const float* __restrict__ Wg,
                             const float* __restrict__ bg, float* __restrict__ gamma) {
  // grid 1536 x 256 threads; each wave computes one output o = b*768 + j
  const int lane = threadIdx.x & 63;
  const int w = threadIdx.x >> 6;
  const int o = blockIdx.x * 4 + w;
  const int b = o / 768;
  const int j = o - b * 768;
  const float* pr = pooled + b * 768;
  const float* wr = Wg + (size_t)j * 768;
  float s = 0.0f;
  #pragma unroll
  for (int c = lane; c < 768; c += 64) s += pr[c] * wr[c];
  #pragma unroll
  for (int off = 32; off > 0; off >>= 1) s += __shfl_down(s, off);
  if (lane == 0) {
    float gin = s + bg[j];
    gamma[o] = fminf(softplusf(gin), 0.05f);
  }
}

// ---------------- W_out -> bf16 ----------------
__global__ void cvt_bf16_kernel(const float* __restrict__ src, unsigned short* __restrict__ dst, int n) {
  int i = blockIdx.x * 256 + threadIdx.x;
  if (i < n) dst[i] = f2bf(src[i]);
}

// ---------------- transpose x [B,N,768] -> xT [B,768,N] ----------------
__global__ __launch_bounds__(256) void transpose_x_kernel(const float* __restrict__ x,
                                                          float* __restrict__ xT) {
  __shared__ float tile[64][65];
  const int c0 = blockIdx.x * 64;   // 12 tiles
  const int n0 = blockIdx.y * 64;   // 64 tiles
  const int b  = blockIdx.z;        // 8
  const int tl = threadIdx.x & 63;
  const int tw = threadIdx.x >> 6;  // 0..3
  const float* src = x + ((size_t)b * 4096 + n0) * 768 + c0;
  #pragma unroll
  for (int j = 0; j < 16; ++j) {
    const int n = j * 4 + tw;
    tile[n][tl] = src[(size_t)n * 768 + tl];
  }
  __syncthreads();
  float* dst = xT + ((size_t)b * 768 + c0) * 4096 + n0;
  #pragma unroll
  for (int j = 0; j < 16; ++j) {
    const int cc = j * 4 + tw;
    dst[(size_t)cc * 4096 + tl] = tile[tl][cc];
  }
}

// ---------------- symplectic reaction-diffusion PDE (register-resident) -----
// Wave w owns rows w*16..w*16+15; lane l owns column l. u[16],v[16] in VGPRs.
// Left/right neighbor: __shfl lane+-1 (periodic). Up/down: registers, except
// strip boundary rows exchanged through a small double-buffered LDS halo.
__global__ __launch_bounds__(256) void pde_kernel(
    const float* __restrict__ xT, const float* __restrict__ gamma,
    const float* __restrict__ alpha, const float* __restrict__ beta,
    const int* __restrict__ kp, unsigned short* __restrict__ uv) {
  __shared__ float haloT[2][4][64];   // [buf][wave][col] = wave's row w*16
  __shared__ float haloB[2][4][64];   // [buf][wave][col] = wave's row w*16+15
  const int c = blockIdx.x;   // channel 0..767
  const int b = blockIdx.y;   // batch 0..7
  const int l = threadIdx.x & 63;
  const int w = threadIdx.x >> 6;   // 0..3

  int ks = *kp; if (ks < 1) ks = 1;
  const float dt = 1.0f / (float)ks;
  const float hdt = 0.5f * dt;
  const float ae = 0.2f * tanhf(alpha[c]);
  const float be = fmaxf(softplusf(beta[c]), 1e-4f);
  const float g = gamma[b * 768 + c];
  const float c1n = -0.5f * dt * g;   // v -= c1*lap  ->  v += c1n*lap
  const float c2p = dt * g;

  const int idxL = (l + 63) & 63;
  const int idxR = (l + 1) & 63;
  const int wu = (w + 1) & 3;   // wave holding rows below (next strip)
  const int wd = (w + 3) & 3;   // wave holding rows above (prev strip)

  float u[16], v[16];
  const float* xp = xT + ((size_t)b * 768 + c) * 4096 + (size_t)(w * 16) * 64 + l;
  #pragma unroll
  for (int r = 0; r < 16; ++r) { u[r] = xp[(size_t)r * 64]; v[r] = 0.0f; }

  int buf = 0;

  // G[r] += COEF * lap(F[r]); one barrier per phase, halo double-buffered.
  #define LAP_PHASE(F, G, COEF)                                              \
    {                                                                        \
      haloT[buf][w][l] = F[0];                                               \
      haloB[buf][w][l] = F[15];                                              \
      __syncthreads();                                                       \
      const float up0  = haloB[buf][wd][l];                                  \
      const float dn15 = haloT[buf][wu][l];                                  \
      _Pragma("unroll")                                                      \
      for (int r = 0; r < 16; ++r) {                                         \
        const float lf = __shfl(F[r], idxL);                                 \
        const float rt = __shfl(F[r], idxR);                                 \
        const float up = (r == 0)  ? up0  : F[r - 1];                        \
        const float dn = (r == 15) ? dn15 : F[r + 1];                        \
        const float lap = (lf + rt) + (up + dn) - 4.0f * F[r];               \
        G[r] = fmaf((COEF), lap, G[r]);                                      \
      }                                                                      \
      buf ^= 1;                                                              \
    }

  for (int s = 0; s < ks; ++s) {
    // reaction, first half-step (pure registers)
    #pragma unroll
    for (int r = 0; r < 16; ++r) {
      const float q = u[r] * u[r] + v[r] * v[r];
      const float rate = fminf(fmaxf(ae - be * q, -1.0f), 1.0f);
      const float t = hdt * rate;
      u[r] = fmaf(t, u[r], u[r]);
      v[r] = fmaf(t, v[r], v[r]);
    }
    // v_half = v - c1*lap(u);  u += c2*lap(v_half);  v = v_half - c1*lap(u)
    LAP_PHASE(u, v, c1n)
    LAP_PHASE(v, u, c2p)
    LAP_PHASE(u, v, c1n)
    // reaction, second half-step
    #pragma unroll
    for (int r = 0; r < 16; ++r) {
      const float q = u[r] * u[r] + v[r] * v[r];
      const float rate = fminf(fmaxf(ae - be * q, -1.0f), 1.0f);
      const float t = hdt * rate;
      u[r] = fmaf(t, u[r], u[r]);
      v[r] = fmaf(t, v[r], v[r]);
    }
  }
  #undef LAP_PHASE

  // write out channel-major bf16: uv[b][c][n] = u, uv[b][768+c][n] = v
  unsigned short* up = uv + ((size_t)b * 1536 + c) * 4096 + (size_t)(w * 16) * 64 + l;
  unsigned short* vp = up + (size_t)768 * 4096;
  #pragma unroll
  for (int r = 0; r < 16; ++r) {
    up[(size_t)r * 64] = f2bf(u[r]);
    vp[(size_t)r * 64] = f2bf(v[r]);
  }
}

// ---------------- transpose uv [8][1536][4096] -> A [32768][1536] ----------------
__global__ void transpose_uv_kernel(const unsigned short* __restrict__ src,
                                    unsigned short* __restrict__ dst) {
  // grid (64, 24, 8), block 256
  __shared__ unsigned short tile[64][66];
  const int n0 = blockIdx.x * 64;
  const int k0 = blockIdx.y * 64;
  const int b = blockIdx.z;
  const int tx = threadIdx.x & 63;
  const int ty = threadIdx.x >> 6;   // 0..3
  const size_t sbase = ((size_t)b * 1536 + k0) * 4096 + n0;
  #pragma unroll
  for (int j = 0; j < 16; ++j) {
    const int k = ty + 4 * j;
    tile[k][tx] = src[sbase + (size_t)k * 4096 + tx];
  }
  __syncthreads();
  const size_t dbase = ((size_t)b * 4096 + n0) * 1536 + k0;
  #pragma unroll
  for (int j = 0; j < 16; ++j) {
    const int n = ty + 4 * j;
    dst[dbase + (size_t)n * 1536 + tx] = tile[tx][n];
  }
}

// ---------------- bf16 MFMA GEMM: out = A @ W^T + x*D ----------------
// LDS tiles are [row][64 halfwords], staged linearly by global_load_lds.
// XOR swizzle (rule #21 both-sides): physical 16B slot p of row r holds
// logical slot (p ^ (r&7)) — achieved by swizzling the per-lane GLOBAL source
// column; fragment reads apply the same XOR. Kills the 16-way bank conflict
// (all quarter-wave lanes previously hit one 16B slot position).
__global__ __launch_bounds__(256) void gemm_kernel(
    const unsigned short* __restrict__ A,   // [32768][1536] bf16
    const unsigned short* __restrict__ Bt,  // [768][1536]  bf16 (W_out, B^T layout)
    const float* __restrict__ x,            // [32768][768]
    const float* __restrict__ Dv,           // [768]
    float* __restrict__ out) {              // [32768][768]
  __shared__ __align__(16) unsigned short Als[128 * 64];
  __shared__ __align__(16) unsigned short Bls[128 * 64];
  const int tid = threadIdx.x;
  const int lane = tid & 63;
  const int w = tid >> 6;       // wave 0..3
  const int wr = w >> 1;        // wave row (2x2 waves, each 64x64 of C)
  const int wc = w & 1;
  const int m0 = blockIdx.x * 128;
  const int n0 = blockIdx.y * 128;

  // staging-side swizzle: lane covers row (lane>>3), phys slot (lane&7);
  // load global logical slot (lane&7)^(lane>>3)
  const int src_col = (((lane & 7) ^ (lane >> 3)) * 8);   // halfwords
  // read-side: quarter-wave q, row-low bits rlow
  const int q = lane >> 4;
  const int rlow = lane & 7;

  float4v acc[4][4];
  #pragma unroll
  for (int a = 0; a < 4; ++a)
    #pragma unroll
    for (int bq = 0; bq < 4; ++bq)
      acc[a][bq] = (float4v){0.f, 0.f, 0.f, 0.f};

  for (int k0 = 0; k0 < 1536; k0 += 64) {
    // stage A-tile [128][64] and B-tile [128][64] via direct global->LDS (16B/lane)
    #pragma unroll
    for (int i = 0; i < 4; ++i) {
      const int rowblk = (w * 4 + i) * 8;        // wave-uniform
      const int row = rowblk + (lane >> 3);
      const int kk = k0 + src_col;
      __builtin_amdgcn_global_load_lds(
          (const __attribute__((address_space(1))) void*)(A + (size_t)(m0 + row) * 1536 + kk),
          (__attribute__((address_space(3))) void*)(&Als[rowblk * 64]), 16, 0, 0);
      __builtin_amdgcn_global_load_lds(
          (const __attribute__((address_space(1))) void*)(Bt + (size_t)(n0 + row) * 1536 + kk),
          (__attribute__((address_space(3))) void*)(&Bls[rowblk * 64]), 16, 0, 0);
    }
    __syncthreads();
    #pragma unroll
    for (int ksub = 0; ksub < 2; ++ksub) {
      const int soff = ((ksub * 4 + q) ^ rlow) * 8;    // swizzled 16B slot (halfwords)
      short8v af[4], bf[4];
      #pragma unroll
      for (int mi = 0; mi < 4; ++mi)
        af[mi] = *(const short8v*)(&Als[(wr * 64 + mi * 16 + (lane & 15)) * 64 + soff]);
      #pragma unroll
      for (int ni = 0; ni < 4; ++ni)
        bf[ni] = *(const short8v*)(&Bls[(wc * 64 + ni * 16 + (lane & 15)) * 64 + soff]);
      #pragma unroll
      for (int mi = 0; mi < 4; ++mi)
        #pragma unroll
        for (int ni = 0; ni < 4; ++ni)
          acc[mi][ni] = __builtin_amdgcn_mfma_f32_16x16x32_bf16(af[mi], bf[ni], acc[mi][ni], 0, 0, 0);
    }
    __syncthreads();
  }

  // epilogue: out = acc + x*D  (C/D layout: col=lane&15, row=(lane>>4)*4+r)
  #pragma unroll
  for (int ni = 0; ni < 4; ++ni) {
    const int col = n0 + wc * 64 + ni * 16 + (lane & 15);
    const float dcol = Dv[col];
    #pragma unroll
    for (int mi = 0; mi < 4; ++mi) {
      #pragma unroll
      for (int r = 0; r < 4; ++r) {
        const int row = m0 + wr * 64 + mi * 16 + (lane >> 4) * 4 + r;
        const size_t idx = (size_t)row * 768 + col;
        out[idx] = acc[mi][ni][r] + x[idx] * dcol;
      }
    }
  }
}

// ---------------------------------------------------------------------------
extern "C" void kernel_launch(void* const* d_in, const int* in_sizes, int n_in,
                              void* d_out, int out_size, void* d_ws, size_t ws_size,
                              hipStream_t stream) {
  const float* x     = (const float*)d_in[0];
  const float* Wg    = (const float*)d_in[1];
  const float* bg    = (const float*)d_in[2];
  const float* alpha = (const float*)d_in[3];
  const float* beta  = (const float*)d_in[4];
  const float* Wout  = (const float*)d_in[5];
  const float* Dv    = (const float*)d_in[6];
  const int*   kp    = (const int*)d_in[7];
  float* out = (float*)d_out;

  // workspace layout (~195 MiB) — xT aliases A (xT dead before A is written)
  char* ws = (char*)d_ws;
  unsigned short* A   = (unsigned short*)(ws);                 // 32768*1536*2   = 100663296
  float* xT           = (float*)(ws);                          // 8*768*4096*4   = 100663296 (alias)
  unsigned short* uv  = (unsigned short*)(ws + 100663296);     // 8*1536*4096*2  = 100663296
  unsigned short* Wb  = (unsigned short*)(ws + 201326592);     // 768*1536*2     = 2359296
  float* partial      = (float*)(ws + 203685888);              // 32*8*768*4     = 786432
  float* pooled       = (float*)(ws + 204472320);              // 6144*4
  float* gam          = (float*)(ws + 204496896);              // 6144*4

  pool_partial_kernel<<<dim3(3, 32, 8), 256, 0, stream>>>(x, partial);
  pool_reduce_kernel<<<24, 256, 0, stream>>>(partial, pooled);
  gamma_kernel<<<1536, 256, 0, stream>>>(pooled, Wg, bg, gam);
  cvt_bf16_kernel<<<(768 * 1536 + 255) / 256, 256, 0, stream>>>(Wout, Wb, 768 * 1536);
  transpose_x_kernel<<<dim3(12, 64, 8), 256, 0, stream>>>(x, xT);
  pde_kernel<<<dim3(768, 8), 256, 0, stream>>>(xT, gam, alpha, beta, kp, uv);
  transpose_uv_kernel<<<dim3(64, 24, 8), 256, 0, stream>>>(uv, A);
  gemm_kernel<<<dim3(256, 6), 256, 0, stream>>>(A, Wb, x, Dv, out);
}

// Round 6
// 375.293 us; speedup vs baseline: 1.1897x; 1.0594x over previous
//
#include <hip/hip_runtime.h>
#include <hip/hip_bf16.h>
#include <math.h>

// ---------------------------------------------------------------------------
// RealSymplecticReactionDiffusion2D — round 5
//  B=8, N=4096 (64x64), d=768, k_steps=4 (read from device)
// Stages:
//  1) transpose_x (FUSED column-sum partials for mean-pool) -> xT + partial
//  2) pool_reduce  -> pooled[8][768]
//  3) gamma_kernel -> gamma[8][768]
//  4) cvt_bf16 (W_out -> bf16)
//  5) pde_kernel: register-resident u/v -> uv bf16 (channel-major)
//  6) transpose_uv -> A [32768][1536] bf16
//  7) gemm_kernel: bf16 MFMA, 128x128 tile, T2 XOR-swizzle (kept, conflict=0),
//     NEW: double-buffered LDS + prefetch-before-compute + raw s_barrier +
//     counted s_waitcnt vmcnt(8)  (T3 minimum-2-phase + T4; never drain to 0
//     in steady state — loads overlap the whole MFMA phase)
//  Aliases: xT ~ A  (xT dead before A written); partial ~ uv (dead before pde)
// ---------------------------------------------------------------------------

typedef __attribute__((ext_vector_type(8))) short short8v;
typedef __attribute__((ext_vector_type(4))) float float4v;

static __device__ __forceinline__ unsigned short f2bf(float f) {
  unsigned u = __builtin_bit_cast(unsigned, f);
  u += 0x7FFFu + ((u >> 16) & 1u);   // round-to-nearest-even
  return (unsigned short)(u >> 16);
}

static __device__ __forceinline__ float softplusf(float x) {
  return (x > 20.0f) ? x : log1pf(expf(x));
}

// ---------------- transpose x [B,N,768] -> xT [B,768,N]  (+ pool partials) --
__global__ __launch_bounds__(256) void transpose_x_kernel(const float* __restrict__ x,
                                                          float* __restrict__ xT,
                                                          float* __restrict__ partial) {
  __shared__ float tile[64][65];
  __shared__ float red[4][64];
  const int c0 = blockIdx.x * 64;   // 12 tiles
  const int n0 = blockIdx.y * 64;   // 64 tiles
  const int b  = blockIdx.z;        // 8
  const int tl = threadIdx.x & 63;
  const int tw = threadIdx.x >> 6;  // 0..3
  const float* src = x + ((size_t)b * 4096 + n0) * 768 + c0;
  float s = 0.0f;
  #pragma unroll
  for (int j = 0; j < 16; ++j) {
    const int n = j * 4 + tw;
    const float val = src[(size_t)n * 768 + tl];
    tile[n][tl] = val;
    s += val;
  }
  red[tw][tl] = s;
  __syncthreads();
  // partial[n-chunk][b][c] ; n-chunk = blockIdx.y (64 chunks)
  if (tw == 0) {
    partial[((size_t)blockIdx.y * 8 + b) * 768 + c0 + tl] =
        red[0][tl] + red[1][tl] + red[2][tl] + red[3][tl];
  }
  float* dst = xT + ((size_t)b * 768 + c0) * 4096 + n0;
  #pragma unroll
  for (int j = 0; j < 16; ++j) {
    const int cc = j * 4 + tw;
    dst[(size_t)cc * 4096 + tl] = tile[tl][cc];
  }
}

__global__ void pool_reduce_kernel(const float* __restrict__ partial, float* __restrict__ pooled) {
  const int idx = blockIdx.x * 256 + threadIdx.x;   // 0..6143 = b*768+c
  float s = 0.0f;
  #pragma unroll
  for (int j = 0; j < 64; ++j) s += partial[(size_t)j * 6144 + idx];
  pooled[idx] = s * (1.0f / 4096.0f);
}

// ---------------- diffusion gate ----------------
__global__ void gamma_kernel(const float* __restrict__ pooled, const float* __restrict__ Wg,
                             const float* __restrict__ bg, float* __restrict__ gamma) {
  // grid 1536 x 256 threads; each wave computes one output o = b*768 + j
  const int lane = threadIdx.x & 63;
  const int w = threadIdx.x >> 6;
  const int o = blockIdx.x * 4 + w;
  const int b = o / 768;
  const int j = o - b * 768;
  const float* pr = pooled + b * 768;
  const float* wr = Wg + (size_t)j * 768;
  float s = 0.0f;
  #pragma unroll
  for (int c = lane; c < 768; c += 64) s += pr[c] * wr[c];
  #pragma unroll
  for (int off = 32; off > 0; off >>= 1) s += __shfl_down(s, off);
  if (lane == 0) {
    float gin = s + bg[j];
    gamma[o] = fminf(softplusf(gin), 0.05f);
  }
}

// ---------------- W_out -> bf16 ----------------
__global__ void cvt_bf16_kernel(const float* __restrict__ src, unsigned short* __restrict__ dst, int n) {
  int i = blockIdx.x * 256 + threadIdx.x;
  if (i < n) dst[i] = f2bf(src[i]);
}

// ---------------- symplectic reaction-diffusion PDE (register-resident) -----
// Wave w owns rows w*16..w*16+15; lane l owns column l. u[16],v[16] in VGPRs.
// Left/right neighbor: __shfl lane+-1 (periodic). Up/down: registers, except
// strip boundary rows exchanged through a small double-buffered LDS halo.
__global__ __launch_bounds__(256) void pde_kernel(
    const float* __restrict__ xT, const float* __restrict__ gamma,
    const float* __restrict__ alpha, const float* __restrict__ beta,
    const int* __restrict__ kp, unsigned short* __restrict__ uv) {
  __shared__ float haloT[2][4][64];   // [buf][wave][col] = wave's row w*16
  __shared__ float haloB[2][4][64];   // [buf][wave][col] = wave's row w*16+15
  const int c = blockIdx.x;   // channel 0..767
  const int b = blockIdx.y;   // batch 0..7
  const int l = threadIdx.x & 63;
  const int w = threadIdx.x >> 6;   // 0..3

  int ks = *kp; if (ks < 1) ks = 1;
  const float dt = 1.0f / (float)ks;
  const float hdt = 0.5f * dt;
  const float ae = 0.2f * tanhf(alpha[c]);
  const float be = fmaxf(softplusf(beta[c]), 1e-4f);
  const float g = gamma[b * 768 + c];
  const float c1n = -0.5f * dt * g;   // v -= c1*lap  ->  v += c1n*lap
  const float c2p = dt * g;

  const int idxL = (l + 63) & 63;
  const int idxR = (l + 1) & 63;
  const int wu = (w + 1) & 3;   // wave holding rows below (next strip)
  const int wd = (w + 3) & 3;   // wave holding rows above (prev strip)

  float u[16], v[16];
  const float* xp = xT + ((size_t)b * 768 + c) * 4096 + (size_t)(w * 16) * 64 + l;
  #pragma unroll
  for (int r = 0; r < 16; ++r) { u[r] = xp[(size_t)r * 64]; v[r] = 0.0f; }

  int buf = 0;

  // G[r] += COEF * lap(F[r]); one barrier per phase, halo double-buffered.
  #define LAP_PHASE(F, G, COEF)                                              \
    {                                                                        \
      haloT[buf][w][l] = F[0];                                               \
      haloB[buf][w][l] = F[15];                                              \
      __syncthreads();                                                       \
      const float up0  = haloB[buf][wd][l];                                  \
      const float dn15 = haloT[buf][wu][l];                                  \
      _Pragma("unroll")                                                      \
      for (int r = 0; r < 16; ++r) {                                         \
        const float lf = __shfl(F[r], idxL);                                 \
        const float rt = __shfl(F[r], idxR);                                 \
        const float up = (r == 0)  ? up0  : F[r - 1];                        \
        const float dn = (r == 15) ? dn15 : F[r + 1];                        \
        const float lap = (lf + rt) + (up + dn) - 4.0f * F[r];               \
        G[r] = fmaf((COEF), lap, G[r]);                                      \
      }                                                                      \
      buf ^= 1;                                                              \
    }

  for (int s = 0; s < ks; ++s) {
    // reaction, first half-step (pure registers)
    #pragma unroll
    for (int r = 0; r < 16; ++r) {
      const float q = u[r] * u[r] + v[r] * v[r];
      const float rate = fminf(fmaxf(ae - be * q, -1.0f), 1.0f);
      const float t = hdt * rate;
      u[r] = fmaf(t, u[r], u[r]);
      v[r] = fmaf(t, v[r], v[r]);
    }
    // v_half = v - c1*lap(u);  u += c2*lap(v_half);  v = v_half - c1*lap(u)
    LAP_PHASE(u, v, c1n)
    LAP_PHASE(v, u, c2p)
    LAP_PHASE(u, v, c1n)
    // reaction, second half-step
    #pragma unroll
    for (int r = 0; r < 16; ++r) {
      const float q = u[r] * u[r] + v[r] * v[r];
      const float rate = fminf(fmaxf(ae - be * q, -1.0f), 1.0f);
      const float t = hdt * rate;
      u[r] = fmaf(t, u[r], u[r]);
      v[r] = fmaf(t, v[r], v[r]);
    }
  }
  #undef LAP_PHASE

  // write out channel-major bf16: uv[b][c][n] = u, uv[b][768+c][n] = v
  unsigned short* up = uv + ((size_t)b * 1536 + c) * 4096 + (size_t)(w * 16) * 64 + l;
  unsigned short* vp = up + (size_t)768 * 4096;
  #pragma unroll
  for (int r = 0; r < 16; ++r) {
    up[(size_t)r * 64] = f2bf(u[r]);
    vp[(size_t)r * 64] = f2bf(v[r]);
  }
}

// ---------------- transpose uv [8][1536][4096] -> A [32768][1536] ----------------
__global__ void transpose_uv_kernel(const unsigned short* __restrict__ src,
                                    unsigned short* __restrict__ dst) {
  // grid (64, 24, 8), block 256
  __shared__ unsigned short tile[64][66];
  const int n0 = blockIdx.x * 64;
  const int k0 = blockIdx.y * 64;
  const int b = blockIdx.z;
  const int tx = threadIdx.x & 63;
  const int ty = threadIdx.x >> 6;   // 0..3
  const size_t sbase = ((size_t)b * 1536 + k0) * 4096 + n0;
  #pragma unroll
  for (int j = 0; j < 16; ++j) {
    const int k = ty + 4 * j;
    tile[k][tx] = src[sbase + (size_t)k * 4096 + tx];
  }
  __syncthreads();
  const size_t dbase = ((size_t)b * 4096 + n0) * 1536 + k0;
  #pragma unroll
  for (int j = 0; j < 16; ++j) {
    const int n = ty + 4 * j;
    dst[dbase + (size_t)n * 1536 + tx] = tile[tx][n];
  }
}

// ---------------- bf16 MFMA GEMM: out = A @ W^T + x*D ----------------
// T2: XOR-swizzled LDS (linear gload_lds dest + inverse-swizzled global src +
//     swizzled read) — bank-conflict-free (verified 2.83e7 -> 0 in R4).
// T3+T4: double-buffered LDS, prefetch next K-tile BEFORE computing current,
//     raw s_barrier pairs + counted s_waitcnt vmcnt(8) (0 only on last tile).
__global__ __launch_bounds__(256) void gemm_kernel(
    const unsigned short* __restrict__ A,   // [32768][1536] bf16
    const unsigned short* __restrict__ Bt,  // [768][1536]  bf16 (W_out, B^T layout)
    const float* __restrict__ x,            // [32768][768]
    const float* __restrict__ Dv,           // [768]
    float* __restrict__ out) {              // [32768][768]
  __shared__ __align__(16) unsigned short Als[2][128 * 64];
  __shared__ __align__(16) unsigned short Bls[2][128 * 64];
  const int tid = threadIdx.x;
  const int lane = tid & 63;
  const int w = tid >> 6;       // wave 0..3
  const int wr = w >> 1;        // wave row (2x2 waves, each 64x64 of C)
  const int wc = w & 1;
  const int m0 = blockIdx.x * 128;
  const int n0 = blockIdx.y * 128;

  // staging-side swizzle: lane covers row (lane>>3), phys slot (lane&7);
  // load global logical slot (lane&7)^(lane>>3)
  const int src_col = (((lane & 7) ^ (lane >> 3)) * 8);   // halfwords
  // read-side: quarter-wave q, row-low bits rlow
  const int q = lane >> 4;
  const int rlow = lane & 7;

  float4v acc[4][4];
  #pragma unroll
  for (int a = 0; a < 4; ++a)
    #pragma unroll
    for (int bq = 0; bq < 4; ++bq)
      acc[a][bq] = (float4v){0.f, 0.f, 0.f, 0.f};

  // per-wave: 8 global_load_lds (4 A + 4 B), 16B each
  #define STAGE(bufi, kbase)                                                  \
    _Pragma("unroll")                                                         \
    for (int i = 0; i < 4; ++i) {                                             \
      const int rowblk = (w * 4 + i) * 8;                                     \
      const int row = rowblk + (lane >> 3);                                   \
      const int kk = (kbase) + src_col;                                       \
      __builtin_amdgcn_global_load_lds(                                       \
          (const __attribute__((address_space(1))) void*)(A + (size_t)(m0 + row) * 1536 + kk), \
          (__attribute__((address_space(3))) void*)(&Als[bufi][rowblk * 64]), 16, 0, 0); \
      __builtin_amdgcn_global_load_lds(                                       \
          (const __attribute__((address_space(1))) void*)(Bt + (size_t)(n0 + row) * 1536 + kk), \
          (__attribute__((address_space(3))) void*)(&Bls[bufi][rowblk * 64]), 16, 0, 0); \
    }

  STAGE(0, 0)
  int cur = 0;
  for (int kt = 0; kt < 24; ++kt) {
    // bar1: all waves' reads of buf[cur^1] (last iter's compute) are retired
    // (guaranteed by their MFMA lgkm dependencies before reaching this point),
    // so re-staging into it is safe.
    __builtin_amdgcn_s_barrier();
    if (kt < 23) {
      STAGE(cur ^ 1, (kt + 1) * 64)
      asm volatile("s_waitcnt vmcnt(8)" ::: "memory");   // wait prev 8, keep new 8 in flight
    } else {
      asm volatile("s_waitcnt vmcnt(0)" ::: "memory");   // last tile: drain
    }
    // bar2: every wave has its current buffer's loads complete
    __builtin_amdgcn_s_barrier();
    __builtin_amdgcn_sched_barrier(0);
    #pragma unroll
    for (int ksub = 0; ksub < 2; ++ksub) {
      const int soff = ((ksub * 4 + q) ^ rlow) * 8;    // swizzled 16B slot (halfwords)
      short8v af[4], bf[4];
      #pragma unroll
      for (int mi = 0; mi < 4; ++mi)
        af[mi] = *(const short8v*)(&Als[cur][(wr * 64 + mi * 16 + (lane & 15)) * 64 + soff]);
      #pragma unroll
      for (int ni = 0; ni < 4; ++ni)
        bf[ni] = *(const short8v*)(&Bls[cur][(wc * 64 + ni * 16 + (lane & 15)) * 64 + soff]);
      #pragma unroll
      for (int mi = 0; mi < 4; ++mi)
        #pragma unroll
        for (int ni = 0; ni < 4; ++ni)
          acc[mi][ni] = __builtin_amdgcn_mfma_f32_16x16x32_bf16(af[mi], bf[ni], acc[mi][ni], 0, 0, 0);
    }
    cur ^= 1;
  }
  #undef STAGE

  // epilogue: out = acc + x*D  (C/D layout: col=lane&15, row=(lane>>4)*4+r)
  #pragma unroll
  for (int ni = 0; ni < 4; ++ni) {
    const int col = n0 + wc * 64 + ni * 16 + (lane & 15);
    const float dcol = Dv[col];
    #pragma unroll
    for (int mi = 0; mi < 4; ++mi) {
      #pragma unroll
      for (int r = 0; r < 4; ++r) {
        const int row = m0 + wr * 64 + mi * 16 + (lane >> 4) * 4 + r;
        const size_t idx = (size_t)row * 768 + col;
        out[idx] = acc[mi][ni][r] + x[idx] * dcol;
      }
    }
  }
}

// ---------------------------------------------------------------------------
extern "C" void kernel_launch(void* const* d_in, const int* in_sizes, int n_in,
                              void* d_out, int out_size, void* d_ws, size_t ws_size,
                              hipStream_t stream) {
  const float* x     = (const float*)d_in[0];
  const float* Wg    = (const float*)d_in[1];
  const float* bg    = (const float*)d_in[2];
  const float* alpha = (const float*)d_in[3];
  const float* beta  = (const float*)d_in[4];
  const float* Wout  = (const float*)d_in[5];
  const float* Dv    = (const float*)d_in[6];
  const int*   kp    = (const int*)d_in[7];
  float* out = (float*)d_out;

  // workspace layout (~195 MiB)
  //   xT  aliases A   (xT dead before A is written by transpose_uv)
  //   partial aliases uv (partial consumed by pool_reduce before pde writes uv)
  char* ws = (char*)d_ws;
  unsigned short* A   = (unsigned short*)(ws);                 // 32768*1536*2   = 100663296
  float* xT           = (float*)(ws);                          // 8*768*4096*4   (alias A)
  unsigned short* uv  = (unsigned short*)(ws + 100663296);     // 8*1536*4096*2  = 100663296
  float* partial      = (float*)(ws + 100663296);              // 64*8*768*4     (alias uv)
  unsigned short* Wb  = (unsigned short*)(ws + 201326592);     // 768*1536*2     = 2359296
  float* pooled       = (float*)(ws + 203685888);              // 6144*4
  float* gam          = (float*)(ws + 203710464);              // 6144*4

  transpose_x_kernel<<<dim3(12, 64, 8), 256, 0, stream>>>(x, xT, partial);
  pool_reduce_kernel<<<24, 256, 0, stream>>>(partial, pooled);
  gamma_kernel<<<1536, 256, 0, stream>>>(pooled, Wg, bg, gam);
  cvt_bf16_kernel<<<(768 * 1536 + 255) / 256, 256, 0, stream>>>(Wout, Wb, 768 * 1536);
  pde_kernel<<<dim3(768, 8), 256, 0, stream>>>(xT, gam, alpha, beta, kp, uv);
  transpose_uv_kernel<<<dim3(64, 24, 8), 256, 0, stream>>>(uv, A);
  gemm_kernel<<<dim3(256, 6), 256, 0, stream>>>(A, Wb, x, Dv, out);
}

// Round 7
// 345.476 us; speedup vs baseline: 1.2924x; 1.0863x over previous
//
#include <hip/hip_runtime.h>
#include <hip/hip_bf16.h>
#include <math.h>

// ---------------------------------------------------------------------------
// RealSymplecticReactionDiffusion2D — round 6
//  B=8, N=4096 (64x64), d=768, k_steps=4 (read from device)
// Stages:
//  1) transpose_x (FUSED column-sum partials for mean-pool) -> xT + partial
//  2) pool_reduce  -> pooled[8][768]
//  3) gamma_kernel -> gamma[8][768]
//  4) cvt_bf16 (W_out -> bf16)
//  5) pde_kernel: register-resident u/v -> uv bf16 (channel-major)
//  6) transpose_uv -> A [32768][1536] bf16
//  7) gemm_kernel: bf16 MFMA, 128x128 tile, T2 XOR-swizzle (conflict=0),
//     dbuf + counted vmcnt(8) (R5), NEW: XCD-chunked block remap — the 6
//     n-blocks sharing an A-panel run consecutively on ONE XCD, so the panel
//     is fetched from HBM once and L2-hit 5x (load latency ~900 -> ~250 cyc,
//     within depth-1 prefetch reach).
//  Aliases: xT ~ A  (xT dead before A written); partial ~ uv (dead before pde)
// ---------------------------------------------------------------------------

typedef __attribute__((ext_vector_type(8))) short short8v;
typedef __attribute__((ext_vector_type(4))) float float4v;

static __device__ __forceinline__ unsigned short f2bf(float f) {
  unsigned u = __builtin_bit_cast(unsigned, f);
  u += 0x7FFFu + ((u >> 16) & 1u);   // round-to-nearest-even
  return (unsigned short)(u >> 16);
}

static __device__ __forceinline__ float softplusf(float x) {
  return (x > 20.0f) ? x : log1pf(expf(x));
}

// ---------------- transpose x [B,N,768] -> xT [B,768,N]  (+ pool partials) --
__global__ __launch_bounds__(256) void transpose_x_kernel(const float* __restrict__ x,
                                                          float* __restrict__ xT,
                                                          float* __restrict__ partial) {
  __shared__ float tile[64][65];
  __shared__ float red[4][64];
  const int c0 = blockIdx.x * 64;   // 12 tiles
  const int n0 = blockIdx.y * 64;   // 64 tiles
  const int b  = blockIdx.z;        // 8
  const int tl = threadIdx.x & 63;
  const int tw = threadIdx.x >> 6;  // 0..3
  const float* src = x + ((size_t)b * 4096 + n0) * 768 + c0;
  float s = 0.0f;
  #pragma unroll
  for (int j = 0; j < 16; ++j) {
    const int n = j * 4 + tw;
    const float val = src[(size_t)n * 768 + tl];
    tile[n][tl] = val;
    s += val;
  }
  red[tw][tl] = s;
  __syncthreads();
  // partial[n-chunk][b][c] ; n-chunk = blockIdx.y (64 chunks)
  if (tw == 0) {
    partial[((size_t)blockIdx.y * 8 + b) * 768 + c0 + tl] =
        red[0][tl] + red[1][tl] + red[2][tl] + red[3][tl];
  }
  float* dst = xT + ((size_t)b * 768 + c0) * 4096 + n0;
  #pragma unroll
  for (int j = 0; j < 16; ++j) {
    const int cc = j * 4 + tw;
    dst[(size_t)cc * 4096 + tl] = tile[tl][cc];
  }
}

__global__ void pool_reduce_kernel(const float* __restrict__ partial, float* __restrict__ pooled) {
  const int idx = blockIdx.x * 256 + threadIdx.x;   // 0..6143 = b*768+c
  float s = 0.0f;
  #pragma unroll
  for (int j = 0; j < 64; ++j) s += partial[(size_t)j * 6144 + idx];
  pooled[idx] = s * (1.0f / 4096.0f);
}

// ---------------- diffusion gate ----------------
__global__ void gamma_kernel(const float* __restrict__ pooled, const float* __restrict__ Wg,
                             const float* __restrict__ bg, float* __restrict__ gamma) {
  // grid 1536 x 256 threads; each wave computes one output o = b*768 + j
  const int lane = threadIdx.x & 63;
  const int w = threadIdx.x >> 6;
  const int o = blockIdx.x * 4 + w;
  const int b = o / 768;
  const int j = o - b * 768;
  const float* pr = pooled + b * 768;
  const float* wr = Wg + (size_t)j * 768;
  float s = 0.0f;
  #pragma unroll
  for (int c = lane; c < 768; c += 64) s += pr[c] * wr[c];
  #pragma unroll
  for (int off = 32; off > 0; off >>= 1) s += __shfl_down(s, off);
  if (lane == 0) {
    float gin = s + bg[j];
    gamma[o] = fminf(softplusf(gin), 0.05f);
  }
}

// ---------------- W_out -> bf16 ----------------
__global__ void cvt_bf16_kernel(const float* __restrict__ src, unsigned short* __restrict__ dst, int n) {
  int i = blockIdx.x * 256 + threadIdx.x;
  if (i < n) dst[i] = f2bf(src[i]);
}

// ---------------- symplectic reaction-diffusion PDE (register-resident) -----
// Wave w owns rows w*16..w*16+15; lane l owns column l. u[16],v[16] in VGPRs.
// Left/right neighbor: __shfl lane+-1 (periodic). Up/down: registers, except
// strip boundary rows exchanged through a small double-buffered LDS halo.
__global__ __launch_bounds__(256) void pde_kernel(
    const float* __restrict__ xT, const float* __restrict__ gamma,
    const float* __restrict__ alpha, const float* __restrict__ beta,
    const int* __restrict__ kp, unsigned short* __restrict__ uv) {
  __shared__ float haloT[2][4][64];   // [buf][wave][col] = wave's row w*16
  __shared__ float haloB[2][4][64];   // [buf][wave][col] = wave's row w*16+15
  const int c = blockIdx.x;   // channel 0..767
  const int b = blockIdx.y;   // batch 0..7
  const int l = threadIdx.x & 63;
  const int w = threadIdx.x >> 6;   // 0..3

  int ks = *kp; if (ks < 1) ks = 1;
  const float dt = 1.0f / (float)ks;
  const float hdt = 0.5f * dt;
  const float ae = 0.2f * tanhf(alpha[c]);
  const float be = fmaxf(softplusf(beta[c]), 1e-4f);
  const float g = gamma[b * 768 + c];
  const float c1n = -0.5f * dt * g;   // v -= c1*lap  ->  v += c1n*lap
  const float c2p = dt * g;

  const int idxL = (l + 63) & 63;
  const int idxR = (l + 1) & 63;
  const int wu = (w + 1) & 3;   // wave holding rows below (next strip)
  const int wd = (w + 3) & 3;   // wave holding rows above (prev strip)

  float u[16], v[16];
  const float* xp = xT + ((size_t)b * 768 + c) * 4096 + (size_t)(w * 16) * 64 + l;
  #pragma unroll
  for (int r = 0; r < 16; ++r) { u[r] = xp[(size_t)r * 64]; v[r] = 0.0f; }

  int buf = 0;

  // G[r] += COEF * lap(F[r]); one barrier per phase, halo double-buffered.
  #define LAP_PHASE(F, G, COEF)                                              \
    {                                                                        \
      haloT[buf][w][l] = F[0];                                               \
      haloB[buf][w][l] = F[15];                                              \
      __syncthreads();                                                       \
      const float up0  = haloB[buf][wd][l];                                  \
      const float dn15 = haloT[buf][wu][l];                                  \
      _Pragma("unroll")                                                      \
      for (int r = 0; r < 16; ++r) {                                         \
        const float lf = __shfl(F[r], idxL);                                 \
        const float rt = __shfl(F[r], idxR);                                 \
        const float up = (r == 0)  ? up0  : F[r - 1];                        \
        const float dn = (r == 15) ? dn15 : F[r + 1];                        \
        const float lap = (lf + rt) + (up + dn) - 4.0f * F[r];               \
        G[r] = fmaf((COEF), lap, G[r]);                                      \
      }                                                                      \
      buf ^= 1;                                                              \
    }

  for (int s = 0; s < ks; ++s) {
    // reaction, first half-step (pure registers)
    #pragma unroll
    for (int r = 0; r < 16; ++r) {
      const float q = u[r] * u[r] + v[r] * v[r];
      const float rate = fminf(fmaxf(ae - be * q, -1.0f), 1.0f);
      const float t = hdt * rate;
      u[r] = fmaf(t, u[r], u[r]);
      v[r] = fmaf(t, v[r], v[r]);
    }
    // v_half = v - c1*lap(u);  u += c2*lap(v_half);  v = v_half - c1*lap(u)
    LAP_PHASE(u, v, c1n)
    LAP_PHASE(v, u, c2p)
    LAP_PHASE(u, v, c1n)
    // reaction, second half-step
    #pragma unroll
    for (int r = 0; r < 16; ++r) {
      const float q = u[r] * u[r] + v[r] * v[r];
      const float rate = fminf(fmaxf(ae - be * q, -1.0f), 1.0f);
      const float t = hdt * rate;
      u[r] = fmaf(t, u[r], u[r]);
      v[r] = fmaf(t, v[r], v[r]);
    }
  }
  #undef LAP_PHASE

  // write out channel-major bf16: uv[b][c][n] = u, uv[b][768+c][n] = v
  unsigned short* up = uv + ((size_t)b * 1536 + c) * 4096 + (size_t)(w * 16) * 64 + l;
  unsigned short* vp = up + (size_t)768 * 4096;
  #pragma unroll
  for (int r = 0; r < 16; ++r) {
    up[(size_t)r * 64] = f2bf(u[r]);
    vp[(size_t)r * 64] = f2bf(v[r]);
  }
}

// ---------------- transpose uv [8][1536][4096] -> A [32768][1536] ----------------
__global__ void transpose_uv_kernel(const unsigned short* __restrict__ src,
                                    unsigned short* __restrict__ dst) {
  // grid (64, 24, 8), block 256
  __shared__ unsigned short tile[64][66];
  const int n0 = blockIdx.x * 64;
  const int k0 = blockIdx.y * 64;
  const int b = blockIdx.z;
  const int tx = threadIdx.x & 63;
  const int ty = threadIdx.x >> 6;   // 0..3
  const size_t sbase = ((size_t)b * 1536 + k0) * 4096 + n0;
  #pragma unroll
  for (int j = 0; j < 16; ++j) {
    const int k = ty + 4 * j;
    tile[k][tx] = src[sbase + (size_t)k * 4096 + tx];
  }
  __syncthreads();
  const size_t dbase = ((size_t)b * 4096 + n0) * 1536 + k0;
  #pragma unroll
  for (int j = 0; j < 16; ++j) {
    const int n = ty + 4 * j;
    dst[dbase + (size_t)n * 1536 + tx] = tile[tx][n];
  }
}

// ---------------- bf16 MFMA GEMM: out = A @ W^T + x*D ----------------
// T2: XOR-swizzled LDS (linear gload_lds dest + inverse-swizzled global src +
//     swizzled read) — bank-conflict-free (verified 2.83e7 -> 0 in R4).
// T3+T4: double-buffered LDS, prefetch next K-tile BEFORE computing current,
//     raw s_barrier pairs + counted s_waitcnt vmcnt(8) (0 only on last tile).
// T1 (new): flattened grid + XCD-chunked remap — the 6 n-blocks of one
//     m-panel are consecutive same-XCD blocks -> A-panel HBM-fetched once,
//     then L2-hit; depth-1 prefetch covers L2 latency.
__global__ __launch_bounds__(256) void gemm_kernel(
    const unsigned short* __restrict__ A,   // [32768][1536] bf16
    const unsigned short* __restrict__ Bt,  // [768][1536]  bf16 (W_out, B^T layout)
    const float* __restrict__ x,            // [32768][768]
    const float* __restrict__ Dv,           // [768]
    float* __restrict__ out) {              // [32768][768]
  __shared__ __align__(16) unsigned short Als[2][128 * 64];
  __shared__ __align__(16) unsigned short Bls[2][128 * 64];
  const int tid = threadIdx.x;
  const int lane = tid & 63;
  const int w = tid >> 6;       // wave 0..3
  const int wr = w >> 1;        // wave row (2x2 waves, each 64x64 of C)
  const int wc = w & 1;

  // XCD-chunked remap: id -> (m-block, n-block). 1536 blocks, 8 XCDs.
  // xcd = id&7 (dispatch round-robin); per-XCD sequence seq = id>>3 walks
  // n fastest -> 6 consecutive same-XCD blocks share one A m-panel.
  const int id = blockIdx.x;
  const int xcd = id & 7;
  const int seq = id >> 3;          // 0..191
  const int nb = seq % 6;
  const int mb = (seq / 6) * 8 + xcd;
  const int m0 = mb * 128;
  const int n0 = nb * 128;

  // staging-side swizzle: lane covers row (lane>>3), phys slot (lane&7);
  // load global logical slot (lane&7)^(lane>>3)
  const int src_col = (((lane & 7) ^ (lane >> 3)) * 8);   // halfwords
  // read-side: quarter-wave q, row-low bits rlow
  const int q = lane >> 4;
  const int rlow = lane & 7;

  float4v acc[4][4];
  #pragma unroll
  for (int a = 0; a < 4; ++a)
    #pragma unroll
    for (int bq = 0; bq < 4; ++bq)
      acc[a][bq] = (float4v){0.f, 0.f, 0.f, 0.f};

  // per-wave: 8 global_load_lds (4 A + 4 B), 16B each
  #define STAGE(bufi, kbase)                                                  \
    _Pragma("unroll")                                                         \
    for (int i = 0; i < 4; ++i) {                                             \
      const int rowblk = (w * 4 + i) * 8;                                     \
      const int row = rowblk + (lane >> 3);                                   \
      const int kk = (kbase) + src_col;                                       \
      __builtin_amdgcn_global_load_lds(                                       \
          (const __attribute__((address_space(1))) void*)(A + (size_t)(m0 + row) * 1536 + kk), \
          (__attribute__((address_space(3))) void*)(&Als[bufi][rowblk * 64]), 16, 0, 0); \
      __builtin_amdgcn_global_load_lds(                                       \
          (const __attribute__((address_space(1))) void*)(Bt + (size_t)(n0 + row) * 1536 + kk), \
          (__attribute__((address_space(3))) void*)(&Bls[bufi][rowblk * 64]), 16, 0, 0); \
    }

  STAGE(0, 0)
  int cur = 0;
  for (int kt = 0; kt < 24; ++kt) {
    // bar1: all waves' reads of buf[cur^1] (last iter's compute) are retired
    // (guaranteed by their MFMA lgkm dependencies before reaching this point),
    // so re-staging into it is safe.
    __builtin_amdgcn_s_barrier();
    if (kt < 23) {
      STAGE(cur ^ 1, (kt + 1) * 64)
      asm volatile("s_waitcnt vmcnt(8)" ::: "memory");   // wait prev 8, keep new 8 in flight
    } else {
      asm volatile("s_waitcnt vmcnt(0)" ::: "memory");   // last tile: drain
    }
    // bar2: every wave has its current buffer's loads complete
    __builtin_amdgcn_s_barrier();
    __builtin_amdgcn_sched_barrier(0);
    #pragma unroll
    for (int ksub = 0; ksub < 2; ++ksub) {
      const int soff = ((ksub * 4 + q) ^ rlow) * 8;    // swizzled 16B slot (halfwords)
      short8v af[4], bf[4];
      #pragma unroll
      for (int mi = 0; mi < 4; ++mi)
        af[mi] = *(const short8v*)(&Als[cur][(wr * 64 + mi * 16 + (lane & 15)) * 64 + soff]);
      #pragma unroll
      for (int ni = 0; ni < 4; ++ni)
        bf[ni] = *(const short8v*)(&Bls[cur][(wc * 64 + ni * 16 + (lane & 15)) * 64 + soff]);
      #pragma unroll
      for (int mi = 0; mi < 4; ++mi)
        #pragma unroll
        for (int ni = 0; ni < 4; ++ni)
          acc[mi][ni] = __builtin_amdgcn_mfma_f32_16x16x32_bf16(af[mi], bf[ni], acc[mi][ni], 0, 0, 0);
    }
    cur ^= 1;
  }
  #undef STAGE

  // epilogue: out = acc + x*D  (C/D layout: col=lane&15, row=(lane>>4)*4+r)
  #pragma unroll
  for (int ni = 0; ni < 4; ++ni) {
    const int col = n0 + wc * 64 + ni * 16 + (lane & 15);
    const float dcol = Dv[col];
    #pragma unroll
    for (int mi = 0; mi < 4; ++mi) {
      #pragma unroll
      for (int r = 0; r < 4; ++r) {
        const int row = m0 + wr * 64 + mi * 16 + (lane >> 4) * 4 + r;
        const size_t idx = (size_t)row * 768 + col;
        out[idx] = acc[mi][ni][r] + x[idx] * dcol;
      }
    }
  }
}

// ---------------------------------------------------------------------------
extern "C" void kernel_launch(void* const* d_in, const int* in_sizes, int n_in,
                              void* d_out, int out_size, void* d_ws, size_t ws_size,
                              hipStream_t stream) {
  const float* x     = (const float*)d_in[0];
  const float* Wg    = (const float*)d_in[1];
  const float* bg    = (const float*)d_in[2];
  const float* alpha = (const float*)d_in[3];
  const float* beta  = (const float*)d_in[4];
  const float* Wout  = (const float*)d_in[5];
  const float* Dv    = (const float*)d_in[6];
  const int*   kp    = (const int*)d_in[7];
  float* out = (float*)d_out;

  // workspace layout (~195 MiB)
  //   xT  aliases A   (xT dead before A is written by transpose_uv)
  //   partial aliases uv (partial consumed by pool_reduce before pde writes uv)
  char* ws = (char*)d_ws;
  unsigned short* A   = (unsigned short*)(ws);                 // 32768*1536*2   = 100663296
  float* xT           = (float*)(ws);                          // 8*768*4096*4   (alias A)
  unsigned short* uv  = (unsigned short*)(ws + 100663296);     // 8*1536*4096*2  = 100663296
  float* partial      = (float*)(ws + 100663296);              // 64*8*768*4     (alias uv)
  unsigned short* Wb  = (unsigned short*)(ws + 201326592);     // 768*1536*2     = 2359296
  float* pooled       = (float*)(ws + 203685888);              // 6144*4
  float* gam          = (float*)(ws + 203710464);              // 6144*4

  transpose_x_kernel<<<dim3(12, 64, 8), 256, 0, stream>>>(x, xT, partial);
  pool_reduce_kernel<<<24, 256, 0, stream>>>(partial, pooled);
  gamma_kernel<<<1536, 256, 0, stream>>>(pooled, Wg, bg, gam);
  cvt_bf16_kernel<<<(768 * 1536 + 255) / 256, 256, 0, stream>>>(Wout, Wb, 768 * 1536);
  pde_kernel<<<dim3(768, 8), 256, 0, stream>>>(xT, gam, alpha, beta, kp, uv);
  transpose_uv_kernel<<<dim3(64, 24, 8), 256, 0, stream>>>(uv, A);
  gemm_kernel<<<1536, 256, 0, stream>>>(A, Wb, x, Dv, out);
}

// Round 8
// 310.732 us; speedup vs baseline: 1.4369x; 1.1118x over previous
//
#include <hip/hip_runtime.h>
#include <hip/hip_bf16.h>
#include <math.h>

// ---------------------------------------------------------------------------
// RealSymplecticReactionDiffusion2D — round 7
//  B=8, N=4096 (64x64), d=768, k_steps=4 (read from device)
// Stages:
//  1) transpose_x (FUSED column-sum partials for mean-pool) -> xT + partial
//  2) pool_reduce  -> pooled[8][768]
//  3) gamma_kernel -> gamma[8][768]
//  4) cvt_bf16 (W_out -> bf16)
//  5) pde_kernel (NEW): ONE WAVE per (b,c) channel — 8x8 lane grid, each lane
//     an 8x8 register patch (u[64],v[64] VGPR). Halo = 32 shfls per lap for
//     the whole 64x64 grid; interior neighbors in-register; NO barriers/LDS.
//  6) transpose_uv -> A [32768][1536] bf16
//  7) gemm_kernel: bf16 MFMA, 128x128 tile, T2 XOR-swizzle (conflict=0),
//     dbuf + counted vmcnt(8), XCD-chunked remap (R6, ~105us).
//  Aliases: xT ~ A  (xT dead before A written); partial ~ uv (dead before pde)
// ---------------------------------------------------------------------------

typedef __attribute__((ext_vector_type(8))) short short8v;
typedef __attribute__((ext_vector_type(4))) float float4v;

static __device__ __forceinline__ unsigned short f2bf(float f) {
  unsigned u = __builtin_bit_cast(unsigned, f);
  u += 0x7FFFu + ((u >> 16) & 1u);   // round-to-nearest-even
  return (unsigned short)(u >> 16);
}

static __device__ __forceinline__ float softplusf(float x) {
  return (x > 20.0f) ? x : log1pf(expf(x));
}

// ---------------- transpose x [B,N,768] -> xT [B,768,N]  (+ pool partials) --
__global__ __launch_bounds__(256) void transpose_x_kernel(const float* __restrict__ x,
                                                          float* __restrict__ xT,
                                                          float* __restrict__ partial) {
  __shared__ float tile[64][65];
  __shared__ float red[4][64];
  const int c0 = blockIdx.x * 64;   // 12 tiles
  const int n0 = blockIdx.y * 64;   // 64 tiles
  const int b  = blockIdx.z;        // 8
  const int tl = threadIdx.x & 63;
  const int tw = threadIdx.x >> 6;  // 0..3
  const float* src = x + ((size_t)b * 4096 + n0) * 768 + c0;
  float s = 0.0f;
  #pragma unroll
  for (int j = 0; j < 16; ++j) {
    const int n = j * 4 + tw;
    const float val = src[(size_t)n * 768 + tl];
    tile[n][tl] = val;
    s += val;
  }
  red[tw][tl] = s;
  __syncthreads();
  // partial[n-chunk][b][c] ; n-chunk = blockIdx.y (64 chunks)
  if (tw == 0) {
    partial[((size_t)blockIdx.y * 8 + b) * 768 + c0 + tl] =
        red[0][tl] + red[1][tl] + red[2][tl] + red[3][tl];
  }
  float* dst = xT + ((size_t)b * 768 + c0) * 4096 + n0;
  #pragma unroll
  for (int j = 0; j < 16; ++j) {
    const int cc = j * 4 + tw;
    dst[(size_t)cc * 4096 + tl] = tile[tl][cc];
  }
}

__global__ void pool_reduce_kernel(const float* __restrict__ partial, float* __restrict__ pooled) {
  const int idx = blockIdx.x * 256 + threadIdx.x;   // 0..6143 = b*768+c
  float s = 0.0f;
  #pragma unroll
  for (int j = 0; j < 64; ++j) s += partial[(size_t)j * 6144 + idx];
  pooled[idx] = s * (1.0f / 4096.0f);
}

// ---------------- diffusion gate ----------------
__global__ void gamma_kernel(const float* __restrict__ pooled, const float* __restrict__ Wg,
                             const float* __restrict__ bg, float* __restrict__ gamma) {
  // grid 1536 x 256 threads; each wave computes one output o = b*768 + j
  const int lane = threadIdx.x & 63;
  const int w = threadIdx.x >> 6;
  const int o = blockIdx.x * 4 + w;
  const int b = o / 768;
  const int j = o - b * 768;
  const float* pr = pooled + b * 768;
  const float* wr = Wg + (size_t)j * 768;
  float s = 0.0f;
  #pragma unroll
  for (int c = lane; c < 768; c += 64) s += pr[c] * wr[c];
  #pragma unroll
  for (int off = 32; off > 0; off >>= 1) s += __shfl_down(s, off);
  if (lane == 0) {
    float gin = s + bg[j];
    gamma[o] = fminf(softplusf(gin), 0.05f);
  }
}

// ---------------- W_out -> bf16 ----------------
__global__ void cvt_bf16_kernel(const float* __restrict__ src, unsigned short* __restrict__ dst, int n) {
  int i = blockIdx.x * 256 + threadIdx.x;
  if (i < n) dst[i] = f2bf(src[i]);
}

// ---------------- symplectic reaction-diffusion PDE (wave-per-channel) ------
// One wave owns one (b,c) 64x64 grid. Lanes form an 8x8 grid (lx=lane&7,
// ly=lane>>3); each lane holds an 8x8 patch in registers: u[64], v[64]
// (cell (r,j) of lane = global row ly*8+r, col lx*8+j). Per lap phase:
// 32 shfls fetch the 4 patch-edge halos from neighbor lanes; interior
// neighbors are in-register. No LDS, no barriers; waves fully independent.
// All u[]/v[]/halo indices are compile-time constants after unroll.
__global__ __launch_bounds__(256, 2) void pde_kernel(
    const float* __restrict__ xT, const float* __restrict__ gamma,
    const float* __restrict__ alpha, const float* __restrict__ beta,
    const int* __restrict__ kp, unsigned short* __restrict__ uv) {
  const int w = threadIdx.x >> 6;          // wave 0..3 (independent channels)
  const int lane = threadIdx.x & 63;
  const int cidx = blockIdx.x * 4 + w;     // 0..6143
  const int b = cidx / 768;
  const int c = cidx - b * 768;
  const int lx = lane & 7;
  const int ly = lane >> 3;

  int ks = *kp; if (ks < 1) ks = 1;
  const float dt = 1.0f / (float)ks;
  const float hdt = 0.5f * dt;
  const float ae = 0.2f * tanhf(alpha[c]);
  const float be = fmaxf(softplusf(beta[c]), 1e-4f);
  const float g = gamma[b * 768 + c];
  const float c1n = -0.5f * dt * g;   // v -= c1*lap  ->  v += c1n*lap
  const float c2p = dt * g;

  const int laneL = (ly << 3) | ((lx + 7) & 7);
  const int laneR = (ly << 3) | ((lx + 1) & 7);
  const int laneU = (((ly + 7) & 7) << 3) | lx;   // holds rows above (row-1)
  const int laneD = (((ly + 1) & 7) << 3) | lx;   // holds rows below (row+1)

  float u[64], v[64];
  const float* xp = xT + ((size_t)b * 768 + c) * 4096;
  #pragma unroll
  for (int r = 0; r < 8; ++r) {
    const float4* src = (const float4*)(xp + (ly * 8 + r) * 64 + lx * 8);
    const float4 a0 = src[0], a1 = src[1];
    u[r * 8 + 0] = a0.x; u[r * 8 + 1] = a0.y; u[r * 8 + 2] = a0.z; u[r * 8 + 3] = a0.w;
    u[r * 8 + 4] = a1.x; u[r * 8 + 5] = a1.y; u[r * 8 + 6] = a1.z; u[r * 8 + 7] = a1.w;
  }
  #pragma unroll
  for (int i = 0; i < 64; ++i) v[i] = 0.0f;

  // G += COEF * lap(F): halo via 32 shfls, interior in-register.
  #define LAP_PHASE(F, G, COEF)                                               \
    {                                                                         \
      float lh[8], rh[8], uh[8], dh[8];                                       \
      _Pragma("unroll")                                                       \
      for (int r = 0; r < 8; ++r) {                                           \
        lh[r] = __shfl(F[r * 8 + 7], laneL);   /* left lane's right col  */   \
        rh[r] = __shfl(F[r * 8 + 0], laneR);   /* right lane's left col  */   \
        uh[r] = __shfl(F[56 + r], laneU);      /* up lane's bottom row, col r */ \
        dh[r] = __shfl(F[r], laneD);           /* down lane's top row, col r  */ \
      }                                                                       \
      _Pragma("unroll")                                                       \
      for (int r = 0; r < 8; ++r) {                                           \
        _Pragma("unroll")                                                     \
        for (int j = 0; j < 8; ++j) {                                         \
          const float lf = (j == 0) ? lh[r] : F[r * 8 + j - 1];               \
          const float rt = (j == 7) ? rh[r] : F[r * 8 + j + 1];               \
          const float up = (r == 0) ? uh[j] : F[(r - 1) * 8 + j];             \
          const float dn = (r == 7) ? dh[j] : F[(r + 1) * 8 + j];             \
          const float lap = (lf + rt) + (up + dn) - 4.0f * F[r * 8 + j];      \
          G[r * 8 + j] = fmaf((COEF), lap, G[r * 8 + j]);                     \
        }                                                                     \
      }                                                                       \
    }

  for (int s = 0; s < ks; ++s) {
    // reaction, first half-step (pure registers)
    #pragma unroll
    for (int i = 0; i < 64; ++i) {
      const float q = u[i] * u[i] + v[i] * v[i];
      const float rate = fminf(fmaxf(ae - be * q, -1.0f), 1.0f);
      const float t = hdt * rate;
      u[i] = fmaf(t, u[i], u[i]);
      v[i] = fmaf(t, v[i], v[i]);
    }
    // v_half = v - c1*lap(u);  u += c2*lap(v_half);  v = v_half - c1*lap(u)
    LAP_PHASE(u, v, c1n)
    LAP_PHASE(v, u, c2p)
    LAP_PHASE(u, v, c1n)
    // reaction, second half-step
    #pragma unroll
    for (int i = 0; i < 64; ++i) {
      const float q = u[i] * u[i] + v[i] * v[i];
      const float rate = fminf(fmaxf(ae - be * q, -1.0f), 1.0f);
      const float t = hdt * rate;
      u[i] = fmaf(t, u[i], u[i]);
      v[i] = fmaf(t, v[i], v[i]);
    }
  }
  #undef LAP_PHASE

  // write out channel-major bf16: uv[b][c][n] = u, uv[b][768+c][n] = v
  unsigned short* up_ = uv + ((size_t)b * 1536 + c) * 4096;
  unsigned short* vp_ = up_ + (size_t)768 * 4096;
  #pragma unroll
  for (int r = 0; r < 8; ++r) {
    const int off = (ly * 8 + r) * 64 + lx * 8;
    short8v us, vs;
    #pragma unroll
    for (int j = 0; j < 8; ++j) {
      us[j] = (short)f2bf(u[r * 8 + j]);
      vs[j] = (short)f2bf(v[r * 8 + j]);
    }
    *(short8v*)(up_ + off) = us;
    *(short8v*)(vp_ + off) = vs;
  }
}

// ---------------- transpose uv [8][1536][4096] -> A [32768][1536] ----------------
__global__ void transpose_uv_kernel(const unsigned short* __restrict__ src,
                                    unsigned short* __restrict__ dst) {
  // grid (64, 24, 8), block 256
  __shared__ unsigned short tile[64][66];
  const int n0 = blockIdx.x * 64;
  const int k0 = blockIdx.y * 64;
  const int b = blockIdx.z;
  const int tx = threadIdx.x & 63;
  const int ty = threadIdx.x >> 6;   // 0..3
  const size_t sbase = ((size_t)b * 1536 + k0) * 4096 + n0;
  #pragma unroll
  for (int j = 0; j < 16; ++j) {
    const int k = ty + 4 * j;
    tile[k][tx] = src[sbase + (size_t)k * 4096 + tx];
  }
  __syncthreads();
  const size_t dbase = ((size_t)b * 4096 + n0) * 1536 + k0;
  #pragma unroll
  for (int j = 0; j < 16; ++j) {
    const int n = ty + 4 * j;
    dst[dbase + (size_t)n * 1536 + tx] = tile[tx][n];
  }
}

// ---------------- bf16 MFMA GEMM: out = A @ W^T + x*D ----------------
// T2: XOR-swizzled LDS (conflict=0, R4). T3+T4: dbuf + counted vmcnt(8) (R5).
// T1: XCD-chunked remap — 6 n-blocks of an m-panel consecutive on one XCD (R6).
__global__ __launch_bounds__(256) void gemm_kernel(
    const unsigned short* __restrict__ A,   // [32768][1536] bf16
    const unsigned short* __restrict__ Bt,  // [768][1536]  bf16 (W_out, B^T layout)
    const float* __restrict__ x,            // [32768][768]
    const float* __restrict__ Dv,           // [768]
    float* __restrict__ out) {              // [32768][768]
  __shared__ __align__(16) unsigned short Als[2][128 * 64];
  __shared__ __align__(16) unsigned short Bls[2][128 * 64];
  const int tid = threadIdx.x;
  const int lane = tid & 63;
  const int w = tid >> 6;       // wave 0..3
  const int wr = w >> 1;        // wave row (2x2 waves, each 64x64 of C)
  const int wc = w & 1;

  // XCD-chunked remap: id -> (m-block, n-block). 1536 blocks, 8 XCDs.
  const int id = blockIdx.x;
  const int xcd = id & 7;
  const int seq = id >> 3;          // 0..191
  const int nb = seq % 6;
  const int mb = (seq / 6) * 8 + xcd;
  const int m0 = mb * 128;
  const int n0 = nb * 128;

  // staging-side swizzle: lane covers row (lane>>3), phys slot (lane&7);
  // load global logical slot (lane&7)^(lane>>3)
  const int src_col = (((lane & 7) ^ (lane >> 3)) * 8);   // halfwords
  // read-side: quarter-wave q, row-low bits rlow
  const int q = lane >> 4;
  const int rlow = lane & 7;

  float4v acc[4][4];
  #pragma unroll
  for (int a = 0; a < 4; ++a)
    #pragma unroll
    for (int bq = 0; bq < 4; ++bq)
      acc[a][bq] = (float4v){0.f, 0.f, 0.f, 0.f};

  // per-wave: 8 global_load_lds (4 A + 4 B), 16B each
  #define STAGE(bufi, kbase)                                                  \
    _Pragma("unroll")                                                         \
    for (int i = 0; i < 4; ++i) {                                             \
      const int rowblk = (w * 4 + i) * 8;                                     \
      const int row = rowblk + (lane >> 3);                                   \
      const int kk = (kbase) + src_col;                                       \
      __builtin_amdgcn_global_load_lds(                                       \
          (const __attribute__((address_space(1))) void*)(A + (size_t)(m0 + row) * 1536 + kk), \
          (__attribute__((address_space(3))) void*)(&Als[bufi][rowblk * 64]), 16, 0, 0); \
      __builtin_amdgcn_global_load_lds(                                       \
          (const __attribute__((address_space(1))) void*)(Bt + (size_t)(n0 + row) * 1536 + kk), \
          (__attribute__((address_space(3))) void*)(&Bls[bufi][rowblk * 64]), 16, 0, 0); \
    }

  STAGE(0, 0)
  int cur = 0;
  for (int kt = 0; kt < 24; ++kt) {
    // bar1: all waves' reads of buf[cur^1] (last iter's compute) are retired
    __builtin_amdgcn_s_barrier();
    if (kt < 23) {
      STAGE(cur ^ 1, (kt + 1) * 64)
      asm volatile("s_waitcnt vmcnt(8)" ::: "memory");   // wait prev 8, keep new 8 in flight
    } else {
      asm volatile("s_waitcnt vmcnt(0)" ::: "memory");   // last tile: drain
    }
    // bar2: every wave has its current buffer's loads complete
    __builtin_amdgcn_s_barrier();
    __builtin_amdgcn_sched_barrier(0);
    #pragma unroll
    for (int ksub = 0; ksub < 2; ++ksub) {
      const int soff = ((ksub * 4 + q) ^ rlow) * 8;    // swizzled 16B slot (halfwords)
      short8v af[4], bf[4];
      #pragma unroll
      for (int mi = 0; mi < 4; ++mi)
        af[mi] = *(const short8v*)(&Als[cur][(wr * 64 + mi * 16 + (lane & 15)) * 64 + soff]);
      #pragma unroll
      for (int ni = 0; ni < 4; ++ni)
        bf[ni] = *(const short8v*)(&Bls[cur][(wc * 64 + ni * 16 + (lane & 15)) * 64 + soff]);
      #pragma unroll
      for (int mi = 0; mi < 4; ++mi)
        #pragma unroll
        for (int ni = 0; ni < 4; ++ni)
          acc[mi][ni] = __builtin_amdgcn_mfma_f32_16x16x32_bf16(af[mi], bf[ni], acc[mi][ni], 0, 0, 0);
    }
    cur ^= 1;
  }
  #undef STAGE

  // epilogue: out = acc + x*D  (C/D layout: col=lane&15, row=(lane>>4)*4+r)
  #pragma unroll
  for (int ni = 0; ni < 4; ++ni) {
    const int col = n0 + wc * 64 + ni * 16 + (lane & 15);
    const float dcol = Dv[col];
    #pragma unroll
    for (int mi = 0; mi < 4; ++mi) {
      #pragma unroll
      for (int r = 0; r < 4; ++r) {
        const int row = m0 + wr * 64 + mi * 16 + (lane >> 4) * 4 + r;
        const size_t idx = (size_t)row * 768 + col;
        out[idx] = acc[mi][ni][r] + x[idx] * dcol;
      }
    }
  }
}

// ---------------------------------------------------------------------------
extern "C" void kernel_launch(void* const* d_in, const int* in_sizes, int n_in,
                              void* d_out, int out_size, void* d_ws, size_t ws_size,
                              hipStream_t stream) {
  const float* x     = (const float*)d_in[0];
  const float* Wg    = (const float*)d_in[1];
  const float* bg    = (const float*)d_in[2];
  const float* alpha = (const float*)d_in[3];
  const float* beta  = (const float*)d_in[4];
  const float* Wout  = (const float*)d_in[5];
  const float* Dv    = (const float*)d_in[6];
  const int*   kp    = (const int*)d_in[7];
  float* out = (float*)d_out;

  // workspace layout (~195 MiB)
  //   xT  aliases A   (xT dead before A is written by transpose_uv)
  //   partial aliases uv (partial consumed by pool_reduce before pde writes uv)
  char* ws = (char*)d_ws;
  unsigned short* A   = (unsigned short*)(ws);                 // 32768*1536*2   = 100663296
  float* xT           = (float*)(ws);                          // 8*768*4096*4   (alias A)
  unsigned short* uv  = (unsigned short*)(ws + 100663296);     // 8*1536*4096*2  = 100663296
  float* partial      = (float*)(ws + 100663296);              // 64*8*768*4     (alias uv)
  unsigned short* Wb  = (unsigned short*)(ws + 201326592);     // 768*1536*2     = 2359296
  float* pooled       = (float*)(ws + 203685888);              // 6144*4
  float* gam          = (float*)(ws + 203710464);              // 6144*4

  transpose_x_kernel<<<dim3(12, 64, 8), 256, 0, stream>>>(x, xT, partial);
  pool_reduce_kernel<<<24, 256, 0, stream>>>(partial, pooled);
  gamma_kernel<<<1536, 256, 0, stream>>>(pooled, Wg, bg, gam);
  cvt_bf16_kernel<<<(768 * 1536 + 255) / 256, 256, 0, stream>>>(Wout, Wb, 768 * 1536);
  pde_kernel<<<1536, 256, 0, stream>>>(xT, gam, alpha, beta, kp, uv);
  transpose_uv_kernel<<<dim3(64, 24, 8), 256, 0, stream>>>(uv, A);
  gemm_kernel<<<1536, 256, 0, stream>>>(A, Wb, x, Dv, out);
}